// Round 7
// baseline (1494.866 us; speedup 1.0000x reference)
//
#include <hip/hip_runtime.h>
#include <math.h>

#define BN_EPS 1e-5f

// ---------------------------------------------------------------------------
// Round 7: fp32 numerics (round-5 proven).  Convs: RT=1, hoisted nbr indices,
// register-double-buffered y lookahead (conv1/2), shallower k-split.
// y0 pre-normalized once (norm0) instead of per-gather.
// ---------------------------------------------------------------------------

__device__ __forceinline__ void fma4(float s, const float4& w, float4& a) {
    a.x = fmaf(s, w.x, a.x);
    a.y = fmaf(s, w.y, a.y);
    a.z = fmaf(s, w.z, a.z);
    a.w = fmaf(s, w.w, a.w);
}

__device__ __forceinline__ float nlr(float x, float sc, float sh) {
    float t = fmaf(x, sc, sh);
    return fmaxf(t, 0.01f * t);
}

__device__ __forceinline__ void bn_coef(const float* __restrict__ sums,
                                        const float* __restrict__ g,
                                        const float* __restrict__ b,
                                        int C, int c, float inv_n,
                                        float& sc, float& sh) {
    float mean = sums[c] * inv_n;
    float var = fmaxf(fmaf(-mean, mean, sums[C + c] * inv_n), 0.f);
    sc = g[c] * rsqrtf(var + BN_EPS);
    sh = fmaf(-mean, sc, b[c]);
}

__global__ void zero_kernel(float* __restrict__ p, int n) {
    int i = blockIdx.x * blockDim.x + threadIdx.x;
    if (i < n) p[i] = 0.f;
}

__global__ void mlp1_kernel(const float* __restrict__ x, const float* __restrict__ w,
                            float* __restrict__ out, int N) {
    int n = blockIdx.x * blockDim.x + threadIdx.x;
    if (n >= N) return;
    float x0 = x[n * 3], x1 = x[n * 3 + 1], x2 = x[n * 3 + 2];
    #pragma unroll
    for (int c4 = 0; c4 < 4; c4++) {
        float4 w0 = *reinterpret_cast<const float4*>(w + 0 + c4 * 4);
        float4 w1 = *reinterpret_cast<const float4*>(w + 16 + c4 * 4);
        float4 w2 = *reinterpret_cast<const float4*>(w + 32 + c4 * 4);
        float4 o;
        o.x = fmaf(x0, w0.x, fmaf(x1, w1.x, x2 * w2.x));
        o.y = fmaf(x0, w0.y, fmaf(x1, w1.y, x2 * w2.y));
        o.z = fmaf(x0, w0.z, fmaf(x1, w1.z, x2 * w2.z));
        o.w = fmaf(x0, w0.w, fmaf(x1, w1.w, x2 * w2.w));
        *reinterpret_cast<float4*>(out + n * 16 + c4 * 4) = o;
    }
}

// per-channel sum & sumsq, float4; requires blockDim % C4 == 0
__global__ void stats4_kernel(const float4* __restrict__ x, int total4, int C, int C4,
                              float* __restrict__ sums) {
    __shared__ float ls[1024];
    int tid = threadIdx.x;
    for (int j = tid; j < 2 * C; j += blockDim.x) ls[j] = 0.f;
    __syncthreads();
    int stride = gridDim.x * blockDim.x;
    int i = blockIdx.x * blockDim.x + tid;
    int c4 = i % C4;
    float4 s = make_float4(0.f, 0.f, 0.f, 0.f);
    float4 q = make_float4(0.f, 0.f, 0.f, 0.f);
    for (; i < total4; i += stride) {
        float4 v = x[i];
        s.x += v.x; s.y += v.y; s.z += v.z; s.w += v.w;
        q.x = fmaf(v.x, v.x, q.x); q.y = fmaf(v.y, v.y, q.y);
        q.z = fmaf(v.z, v.z, q.z); q.w = fmaf(v.w, v.w, q.w);
    }
    int cb = c4 * 4;
    atomicAdd(&ls[cb + 0], s.x); atomicAdd(&ls[cb + 1], s.y);
    atomicAdd(&ls[cb + 2], s.z); atomicAdd(&ls[cb + 3], s.w);
    atomicAdd(&ls[C + cb + 0], q.x); atomicAdd(&ls[C + cb + 1], q.y);
    atomicAdd(&ls[C + cb + 2], q.z); atomicAdd(&ls[C + cb + 3], q.w);
    __syncthreads();
    for (int j = tid; j < 2 * C; j += blockDim.x) atomicAdd(&sums[j], ls[j]);
}

// in-place BN+lrelu on fp32 y0 (C=16); one float4 per thread
__global__ void norm0_kernel(float4* __restrict__ y, int total4,
                             const float* __restrict__ sums, const float* __restrict__ g,
                             const float* __restrict__ b, float inv_n) {
    __shared__ float lsc[16], lsh[16];
    int tid = threadIdx.x;
    if (tid < 16) {
        float sc, sh;
        bn_coef(sums, g, b, 16, tid, inv_n, sc, sh);
        lsc[tid] = sc;
        lsh[tid] = sh;
    }
    __syncthreads();
    int i = blockIdx.x * blockDim.x + tid;
    if (i >= total4) return;
    int cb = (i & 3) * 4;
    float4 v = y[i];
    v.x = nlr(v.x, lsc[cb + 0], lsh[cb + 0]);
    v.y = nlr(v.y, lsc[cb + 1], lsh[cb + 1]);
    v.z = nlr(v.z, lsc[cb + 2], lsh[cb + 2]);
    v.w = nlr(v.w, lsc[cb + 3], lsh[cb + 3]);
    y[i] = v;
}

// reduce KS k-split partial slices + fused stats; out aliases slice 0
template <int C, int KS>
__global__ void reducek_kernel(const float4* __restrict__ in, float4* __restrict__ out,
                               int total4, float* __restrict__ sums) {
    __shared__ float ls[1024];
    constexpr int C4 = C / 4;
    int tid = threadIdx.x;
    for (int j = tid; j < 2 * C; j += blockDim.x) ls[j] = 0.f;
    __syncthreads();
    int stride = gridDim.x * blockDim.x;
    int i = blockIdx.x * blockDim.x + tid;
    int c4 = i % C4;
    float4 s = make_float4(0.f, 0.f, 0.f, 0.f);
    float4 q = make_float4(0.f, 0.f, 0.f, 0.f);
    for (; i < total4; i += stride) {
        float4 v = make_float4(0.f, 0.f, 0.f, 0.f);
        #pragma unroll
        for (int p = 0; p < KS; p++) {
            float4 t = in[(size_t)p * total4 + i];
            v.x += t.x; v.y += t.y; v.z += t.z; v.w += t.w;
        }
        out[i] = v;
        s.x += v.x; s.y += v.y; s.z += v.z; s.w += v.w;
        q.x = fmaf(v.x, v.x, q.x); q.y = fmaf(v.y, v.y, q.y);
        q.z = fmaf(v.z, v.z, q.z); q.w = fmaf(v.w, v.w, q.w);
    }
    int cb = c4 * 4;
    atomicAdd(&ls[cb + 0], s.x); atomicAdd(&ls[cb + 1], s.y);
    atomicAdd(&ls[cb + 2], s.z); atomicAdd(&ls[cb + 3], s.w);
    atomicAdd(&ls[C + cb + 0], q.x); atomicAdd(&ls[C + cb + 1], q.y);
    atomicAdd(&ls[C + cb + 2], q.z); atomicAdd(&ls[C + cb + 3], q.w);
    __syncthreads();
    for (int j = tid; j < 2 * C; j += blockDim.x) atomicAdd(&sums[j], ls[j]);
}

// ---------------------------------------------------------------------------
// Direct sparse conv, fp32 normalized input.  grid = NCOT*MT*KS.
// RT=1 rows/thread; PREF: hoisted nbr indices + double-buffered y lookahead.
// ---------------------------------------------------------------------------
template <int CIN, int COUT, int CO_TILE, int NCOT, int MT, int TM, int NTHR,
          int NQ, int KT, bool STATS, bool PREF>
__global__ __launch_bounds__(NTHR) void convd_kernel(
    const float* __restrict__ y, const int* __restrict__ nbr,
    const float* __restrict__ w, float* __restrict__ out,
    float* __restrict__ s_out) {
    constexpr int CQT = CO_TILE / (4 * NQ);
    constexpr int MGRP = NTHR / CQT;
    constexpr int RT = TM / MGRP;
    constexpr int C4N = CIN / 4;
    static_assert(MGRP * RT == TM, "tile mismatch");
    static_assert(MGRP * CQT == NTHR, "thread mismatch");
    static_assert(!PREF || RT == 1, "PREF requires RT==1");

    __shared__ float sred[STATS ? 2 * CO_TILE : 1];

    const int tid = threadIdx.x;
    const int bid = blockIdx.x;
    const int cot = bid % NCOT;
    const int rest = bid / NCOT;
    const int mt = rest % MT;
    const int ks = rest / MT;
    const int m0 = mt * TM;
    const int cobase = cot * CO_TILE;
    const int k0 = ks * KT;
    const int cq = tid % CQT;
    const int mg = tid / CQT;

    float4 acc[RT][NQ];
    #pragma unroll
    for (int r = 0; r < RT; r++)
        #pragma unroll
        for (int q = 0; q < NQ; q++) acc[r][q] = make_float4(0.f, 0.f, 0.f, 0.f);

    if constexpr (PREF) {
        const int mrow = m0 + mg;
        int idxs[KT];
        #pragma unroll
        for (int kk = 0; kk < KT; kk++)
            idxs[kk] = nbr[(size_t)mrow * 27 + k0 + kk];

        auto ldy = [&](int row, float4 (&yv)[C4N]) {
            #pragma unroll
            for (int c4 = 0; c4 < C4N; c4++)
                yv[c4] = *reinterpret_cast<const float4*>(
                    y + (size_t)row * CIN + c4 * 4);
        };
        auto fmak = [&](int k, const float4 (&yv)[C4N]) {
            const float* wk = w + (size_t)k * CIN * COUT + cobase + cq * (4 * NQ);
            #pragma unroll
            for (int c4 = 0; c4 < C4N; c4++) {
                #pragma unroll
                for (int jj = 0; jj < 4; jj++) {
                    float e = jj == 0 ? yv[c4].x : jj == 1 ? yv[c4].y
                             : jj == 2 ? yv[c4].z : yv[c4].w;
                    #pragma unroll
                    for (int q = 0; q < NQ; q++) {
                        float4 wv = *reinterpret_cast<const float4*>(
                            wk + (size_t)(c4 * 4 + jj) * COUT + q * 4);
                        fma4(e, wv, acc[0][q]);
                    }
                }
            }
        };
        float4 ya[C4N], yb[C4N];
        ldy(idxs[0], ya);
        int kk = 0;
        for (; kk + 2 <= KT; kk += 2) {
            ldy(idxs[kk + 1], yb);
            fmak(k0 + kk, ya);
            if (kk + 2 < KT) ldy(idxs[kk + 2], ya);
            fmak(k0 + kk + 1, yb);
        }
        if (KT & 1) fmak(k0 + KT - 1, ya);
    } else {
        int mrow[RT];
        #pragma unroll
        for (int r = 0; r < RT; r++) mrow[r] = m0 + mg + r * MGRP;
        int rows[RT];
        #pragma unroll
        for (int r = 0; r < RT; r++) rows[r] = nbr[(size_t)mrow[r] * 27 + k0];
        for (int kk = k0; kk < k0 + KT; kk++) {
            int rnext[RT];
            if (kk + 1 < k0 + KT) {
                #pragma unroll
                for (int r = 0; r < RT; r++)
                    rnext[r] = nbr[(size_t)mrow[r] * 27 + kk + 1];
            }
            const float* wk = w + (size_t)kk * CIN * COUT + cobase + cq * (4 * NQ);
            #pragma unroll 4
            for (int c4 = 0; c4 < C4N; c4++) {
                float4 yv[RT];
                #pragma unroll
                for (int r = 0; r < RT; r++)
                    yv[r] = *reinterpret_cast<const float4*>(
                        y + (size_t)rows[r] * CIN + c4 * 4);
                #pragma unroll
                for (int jj = 0; jj < 4; jj++) {
                    #pragma unroll
                    for (int q = 0; q < NQ; q++) {
                        float4 wv = *reinterpret_cast<const float4*>(
                            wk + (size_t)(c4 * 4 + jj) * COUT + q * 4);
                        #pragma unroll
                        for (int r = 0; r < RT; r++) {
                            float e = jj == 0 ? yv[r].x : jj == 1 ? yv[r].y
                                     : jj == 2 ? yv[r].z : yv[r].w;
                            fma4(e, wv, acc[r][q]);
                        }
                    }
                }
            }
            #pragma unroll
            for (int r = 0; r < RT; r++) rows[r] = rnext[r];
        }
    }

    float* outp = out + (size_t)ks * MT * TM * COUT;
    #pragma unroll
    for (int r = 0; r < RT; r++)
        #pragma unroll
        for (int q = 0; q < NQ; q++)
            *reinterpret_cast<float4*>(
                outp + (size_t)(m0 + mg + r * MGRP) * COUT + cobase + cq * (4 * NQ) + q * 4) =
                acc[r][q];

    if constexpr (STATS) {
        for (int j = tid; j < 2 * CO_TILE; j += NTHR) sred[j] = 0.f;
        __syncthreads();
        #pragma unroll
        for (int q = 0; q < NQ; q++) {
            float4 s = make_float4(0.f, 0.f, 0.f, 0.f);
            float4 qq = make_float4(0.f, 0.f, 0.f, 0.f);
            #pragma unroll
            for (int r = 0; r < RT; r++) {
                float4 v = acc[r][q];
                s.x += v.x; s.y += v.y; s.z += v.z; s.w += v.w;
                qq.x = fmaf(v.x, v.x, qq.x); qq.y = fmaf(v.y, v.y, qq.y);
                qq.z = fmaf(v.z, v.z, qq.z); qq.w = fmaf(v.w, v.w, qq.w);
            }
            int cb = cq * (4 * NQ) + q * 4;
            atomicAdd(&sred[cb + 0], s.x); atomicAdd(&sred[cb + 1], s.y);
            atomicAdd(&sred[cb + 2], s.z); atomicAdd(&sred[cb + 3], s.w);
            atomicAdd(&sred[CO_TILE + cb + 0], qq.x);
            atomicAdd(&sred[CO_TILE + cb + 1], qq.y);
            atomicAdd(&sred[CO_TILE + cb + 2], qq.z);
            atomicAdd(&sred[CO_TILE + cb + 3], qq.w);
        }
        __syncthreads();
        for (int j = tid; j < CO_TILE; j += NTHR) {
            atomicAdd(&s_out[cobase + j], sred[j]);
            atomicAdd(&s_out[COUT + cobase + j], sred[CO_TILE + j]);
        }
    }
}

// ---------------------------------------------------------------------------
// down (concat + 1x1): in1 = normalized fp32 y, in2 = raw conv out (normalized
// inline via LDS coefs).  Fused output stats.
// ---------------------------------------------------------------------------
template <int C1, int C2, int COUT, int NQ, int NTHR>
__global__ __launch_bounds__(NTHR) void down3_kernel(
    const float* __restrict__ in1, const float* __restrict__ in2,
    const float* __restrict__ w, float* __restrict__ out,
    const float* __restrict__ s2, const float* __restrict__ g2,
    const float* __restrict__ b2, float inv2,
    float* __restrict__ s_out) {
    constexpr int CQT = COUT / (4 * NQ);
    constexpr int PAIRS = NTHR / CQT;
    __shared__ __align__(16) float n2c[C2], n2h[C2];
    __shared__ float sred[2 * COUT];

    const int tid = threadIdx.x;
    for (int c = tid; c < C2; c += NTHR) {
        float sc, sh;
        bn_coef(s2, g2, b2, C2, c, inv2, sc, sh);
        n2c[c] = sc; n2h[c] = sh;
    }
    for (int j = tid; j < 2 * COUT; j += NTHR) sred[j] = 0.f;
    __syncthreads();

    const int cq = tid % CQT;
    const int pr = tid / CQT;
    const int n0 = (blockIdx.x * PAIRS + pr) * 2;

    float4 acc[2][NQ];
    #pragma unroll
    for (int r = 0; r < 2; r++)
        #pragma unroll
        for (int q = 0; q < NQ; q++) acc[r][q] = make_float4(0.f, 0.f, 0.f, 0.f);

    const float* w1 = w + cq * (4 * NQ);
    #pragma unroll 8
    for (int ci4 = 0; ci4 < C1 / 4; ci4++) {
        float4 a0 = *reinterpret_cast<const float4*>(in1 + (size_t)n0 * C1 + ci4 * 4);
        float4 a1 = *reinterpret_cast<const float4*>(in1 + (size_t)(n0 + 1) * C1 + ci4 * 4);
        #pragma unroll
        for (int jj = 0; jj < 4; jj++) {
            const float* wp = w1 + (size_t)(ci4 * 4 + jj) * COUT;
            float e0 = jj == 0 ? a0.x : jj == 1 ? a0.y : jj == 2 ? a0.z : a0.w;
            float e1 = jj == 0 ? a1.x : jj == 1 ? a1.y : jj == 2 ? a1.z : a1.w;
            #pragma unroll
            for (int q = 0; q < NQ; q++) {
                float4 wv = *reinterpret_cast<const float4*>(wp + q * 4);
                fma4(e0, wv, acc[0][q]);
                fma4(e1, wv, acc[1][q]);
            }
        }
    }
    const float* w2 = w + (size_t)C1 * COUT + cq * (4 * NQ);
    #pragma unroll 8
    for (int ci4 = 0; ci4 < C2 / 4; ci4++) {
        float4 a0 = *reinterpret_cast<const float4*>(in2 + (size_t)n0 * C2 + ci4 * 4);
        float4 a1 = *reinterpret_cast<const float4*>(in2 + (size_t)(n0 + 1) * C2 + ci4 * 4);
        float4 sc = *reinterpret_cast<const float4*>(&n2c[ci4 * 4]);
        float4 sh = *reinterpret_cast<const float4*>(&n2h[ci4 * 4]);
        a0.x = nlr(a0.x, sc.x, sh.x); a0.y = nlr(a0.y, sc.y, sh.y);
        a0.z = nlr(a0.z, sc.z, sh.z); a0.w = nlr(a0.w, sc.w, sh.w);
        a1.x = nlr(a1.x, sc.x, sh.x); a1.y = nlr(a1.y, sc.y, sh.y);
        a1.z = nlr(a1.z, sc.z, sh.z); a1.w = nlr(a1.w, sc.w, sh.w);
        #pragma unroll
        for (int jj = 0; jj < 4; jj++) {
            const float* wp = w2 + (size_t)(ci4 * 4 + jj) * COUT;
            float e0 = jj == 0 ? a0.x : jj == 1 ? a0.y : jj == 2 ? a0.z : a0.w;
            float e1 = jj == 0 ? a1.x : jj == 1 ? a1.y : jj == 2 ? a1.z : a1.w;
            #pragma unroll
            for (int q = 0; q < NQ; q++) {
                float4 wv = *reinterpret_cast<const float4*>(wp + q * 4);
                fma4(e0, wv, acc[0][q]);
                fma4(e1, wv, acc[1][q]);
            }
        }
    }
    #pragma unroll
    for (int r = 0; r < 2; r++)
        #pragma unroll
        for (int q = 0; q < NQ; q++)
            *reinterpret_cast<float4*>(out + (size_t)(n0 + r) * COUT + cq * (4 * NQ) + q * 4) =
                acc[r][q];

    #pragma unroll
    for (int q = 0; q < NQ; q++) {
        float4 s = make_float4(0.f, 0.f, 0.f, 0.f);
        float4 qq = make_float4(0.f, 0.f, 0.f, 0.f);
        #pragma unroll
        for (int r = 0; r < 2; r++) {
            float4 v = acc[r][q];
            s.x += v.x; s.y += v.y; s.z += v.z; s.w += v.w;
            qq.x = fmaf(v.x, v.x, qq.x); qq.y = fmaf(v.y, v.y, qq.y);
            qq.z = fmaf(v.z, v.z, qq.z); qq.w = fmaf(v.w, v.w, qq.w);
        }
        int cb = cq * (4 * NQ) + q * 4;
        atomicAdd(&sred[cb + 0], s.x); atomicAdd(&sred[cb + 1], s.y);
        atomicAdd(&sred[cb + 2], s.z); atomicAdd(&sred[cb + 3], s.w);
        atomicAdd(&sred[COUT + cb + 0], qq.x);
        atomicAdd(&sred[COUT + cb + 1], qq.y);
        atomicAdd(&sred[COUT + cb + 2], qq.z);
        atomicAdd(&sred[COUT + cb + 3], qq.w);
    }
    __syncthreads();
    for (int j = tid; j < COUT; j += NTHR) {
        atomicAdd(&s_out[j], sred[j]);
        atomicAdd(&s_out[COUT + j], sred[COUT + j]);
    }
}

// ---------------------------------------------------------------------------
// pool: min/max over 27 raw rows, BN+lrelu by scale sign -> normalized y
// ---------------------------------------------------------------------------
template <int C, int NTHR>
__global__ __launch_bounds__(NTHR) void pool2_kernel(
    const float* __restrict__ draw, const int* __restrict__ pmap,
    const float* __restrict__ sums, const float* __restrict__ g,
    const float* __restrict__ b, float inv_n,
    float* __restrict__ yout, int Nout) {
    constexpr int C4 = C / 4;
    int i = blockIdx.x * NTHR + threadIdx.x;
    if (i >= Nout * C4) return;
    int n = i / C4, c4 = i % C4;
    float sc[4], sh[4];
    #pragma unroll
    for (int j = 0; j < 4; j++) bn_coef(sums, g, b, C, c4 * 4 + j, inv_n, sc[j], sh[j]);
    const int* pm = pmap + n * 27;
    float4 mn = make_float4(INFINITY, INFINITY, INFINITY, INFINITY);
    float4 mx = make_float4(-INFINITY, -INFINITY, -INFINITY, -INFINITY);
    #pragma unroll 9
    for (int k = 0; k < 27; k++) {
        int row = pm[k];
        float4 v = *reinterpret_cast<const float4*>(draw + (size_t)row * C + c4 * 4);
        mn.x = fminf(mn.x, v.x); mn.y = fminf(mn.y, v.y);
        mn.z = fminf(mn.z, v.z); mn.w = fminf(mn.w, v.w);
        mx.x = fmaxf(mx.x, v.x); mx.y = fmaxf(mx.y, v.y);
        mx.z = fmaxf(mx.z, v.z); mx.w = fmaxf(mx.w, v.w);
    }
    float4 o;
    o.x = nlr(sc[0] >= 0.f ? mx.x : mn.x, sc[0], sh[0]);
    o.y = nlr(sc[1] >= 0.f ? mx.y : mn.y, sc[1], sh[1]);
    o.z = nlr(sc[2] >= 0.f ? mx.z : mn.z, sc[2], sh[2]);
    o.w = nlr(sc[3] >= 0.f ? mx.w : mn.w, sc[3], sh[3]);
    *reinterpret_cast<float4*>(yout + (size_t)n * C + c4 * 4) = o;
}

__global__ void segpool2_kernel(const float* __restrict__ y,
                                const float* __restrict__ sums,
                                const float* __restrict__ g, const float* __restrict__ b,
                                float inv_n, float* __restrict__ z) {
    int bi = blockIdx.x;
    int c = threadIdx.x;  // 512
    float sc, sh;
    bn_coef(sums, g, b, 512, c, inv_n, sc, sh);
    float mn = INFINITY, mx = -INFINITY, sm = 0.f;
    for (int r = 0; r < 32; r++) {
        float v = y[(size_t)(bi * 32 + r) * 512 + c];
        mn = fminf(mn, v);
        mx = fmaxf(mx, v);
        sm += nlr(v, sc, sh);
    }
    z[bi * 1024 + c] = nlr(sc >= 0.f ? mx : mn, sc, sh);
    z[bi * 1024 + 512 + c] = sm * (1.f / 32.f);
}

// FC (M=8): grid (COUT/64, KSPLIT); optional input normalization at staging
template <int K, int COUT, int KSPLIT, bool NORM>
__global__ __launch_bounds__(256) void fc_kernel(
    const float* __restrict__ z, const float* __restrict__ w,
    const float* __restrict__ ns, const float* __restrict__ ng,
    const float* __restrict__ nb, float inv_n,
    float* __restrict__ out) {
    constexpr int KC = K / KSPLIT;
    constexpr int KG = KC / 16;
    __shared__ __align__(16) float zt[KC * 8];
    __shared__ float red[16 * 520];

    const int cobase = blockIdx.x * 64;
    const int kc0 = blockIdx.y * KC;
    const int tid = threadIdx.x;
    const int coq = tid & 15;
    const int kg = tid >> 4;

    for (int idx = tid; idx < 8 * (KC / 4); idx += 256) {
        int n = idx / (KC / 4);
        int kq = idx - n * (KC / 4);
        float4 v = *reinterpret_cast<const float4*>(z + (size_t)n * K + kc0 + kq * 4);
        if constexpr (NORM) {
            #pragma unroll
            for (int j = 0; j < 4; j++) {
                float sc, sh;
                bn_coef(ns, ng, nb, K, kc0 + kq * 4 + j, inv_n, sc, sh);
                float* pv = j == 0 ? &v.x : j == 1 ? &v.y : j == 2 ? &v.z : &v.w;
                *pv = nlr(*pv, sc, sh);
            }
        }
        zt[(kq * 4 + 0) * 8 + n] = v.x;
        zt[(kq * 4 + 1) * 8 + n] = v.y;
        zt[(kq * 4 + 2) * 8 + n] = v.z;
        zt[(kq * 4 + 3) * 8 + n] = v.w;
    }
    __syncthreads();

    float4 acc[8];
    #pragma unroll
    for (int n = 0; n < 8; n++) acc[n] = make_float4(0.f, 0.f, 0.f, 0.f);
    for (int ki = 0; ki < KG; ki++) {
        int k = kg * KG + ki;
        float4 wv = *reinterpret_cast<const float4*>(
            w + (size_t)(kc0 + k) * COUT + cobase + coq * 4);
        float4 za = *reinterpret_cast<const float4*>(&zt[k * 8]);
        float4 zb = *reinterpret_cast<const float4*>(&zt[k * 8 + 4]);
        fma4(za.x, wv, acc[0]); fma4(za.y, wv, acc[1]);
        fma4(za.z, wv, acc[2]); fma4(za.w, wv, acc[3]);
        fma4(zb.x, wv, acc[4]); fma4(zb.y, wv, acc[5]);
        fma4(zb.z, wv, acc[6]); fma4(zb.w, wv, acc[7]);
    }
    #pragma unroll
    for (int n = 0; n < 8; n++) {
        red[kg * 520 + (coq * 4 + 0) * 8 + n] = acc[n].x;
        red[kg * 520 + (coq * 4 + 1) * 8 + n] = acc[n].y;
        red[kg * 520 + (coq * 4 + 2) * 8 + n] = acc[n].z;
        red[kg * 520 + (coq * 4 + 3) * 8 + n] = acc[n].w;
    }
    __syncthreads();
    for (int oi = tid; oi < 512; oi += 256) {
        int c = oi >> 3;
        int n = oi & 7;
        float s = 0.f;
        #pragma unroll
        for (int gg = 0; gg < 16; gg++) s += red[gg * 520 + c * 8 + n];
        float* op = out + (size_t)n * COUT + cobase + c;
        if (KSPLIT > 1) atomicAdd(op, s);
        else *op = s;
    }
}

__global__ void f3n_kernel(const float* __restrict__ in, const float* __restrict__ w,
                           const float* __restrict__ bias,
                           const float* __restrict__ sums, const float* __restrict__ g,
                           const float* __restrict__ b, float inv_n,
                           float* __restrict__ out) {
    __shared__ float zin[8 * 256];
    int tid = threadIdx.x;  // 256
    for (int idx = tid; idx < 2048; idx += 256) {
        int c = idx & 255;
        float sc, sh;
        bn_coef(sums, g, b, 256, c, inv_n, sc, sh);
        zin[idx] = nlr(in[idx], sc, sh);
    }
    __syncthreads();
    if (tid >= 160) return;
    int n = tid / 20, co = tid % 20;
    float acc = bias[co];
    for (int ci = 0; ci < 256; ci++)
        acc = fmaf(zin[n * 256 + ci], w[ci * 20 + co], acc);
    out[tid] = acc;
}

// ---------------------------------------------------------------------------

extern "C" void kernel_launch(void* const* d_in, const int* in_sizes, int n_in,
                              void* d_out, int out_size, void* d_ws, size_t ws_size,
                              hipStream_t stream) {
    (void)in_sizes; (void)n_in; (void)out_size; (void)ws_size;

    const int N0 = 131072, N1 = 32768, N2 = 8192, N3 = 2048, N4 = 512, N5 = 256;

    const float* x      = (const float*)d_in[0];
    const float* w_mlp1 = (const float*)d_in[1];
    const float* g_mlp1 = (const float*)d_in[2];
    const float* b_mlp1 = (const float*)d_in[3];
    const float* w_c[6]; const float* g_c[6]; const float* b_c[6];
    for (int i = 0; i < 6; i++) {
        w_c[i] = (const float*)d_in[4 + 3 * i];
        g_c[i] = (const float*)d_in[5 + 3 * i];
        b_c[i] = (const float*)d_in[6 + 3 * i];
    }
    const float* w_d[5]; const float* g_d[5]; const float* b_d[5];
    for (int i = 0; i < 5; i++) {
        w_d[i] = (const float*)d_in[22 + 3 * i];
        g_d[i] = (const float*)d_in[23 + 3 * i];
        b_d[i] = (const float*)d_in[24 + 3 * i];
    }
    const float* w_f1 = (const float*)d_in[37];
    const float* g_f1 = (const float*)d_in[38];
    const float* b_f1 = (const float*)d_in[39];
    const float* w_f2 = (const float*)d_in[40];
    const float* g_f2 = (const float*)d_in[41];
    const float* b_f2 = (const float*)d_in[42];
    const float* w_f3 = (const float*)d_in[43];
    const float* bias_f3 = (const float*)d_in[44];
    const int* nbr[6];
    for (int i = 0; i < 6; i++) nbr[i] = (const int*)d_in[45 + i];
    const int* pool[5];
    for (int i = 0; i < 5; i++) pool[i] = (const int*)d_in[51 + i];

    float* ws    = (float*)d_ws;
    float* bufA  = ws;                    // normalized y levels
    float* bufB  = bufA + 2097152;        // conv finals + partial arena
    float* bufC  = bufB + 4194304;        // down raw / z / partial spill
    float* stats = bufC + 4194304;
    float* out = (float*)d_out;

    auto st = [&](int slot) { return stats + slot * 1024; };

    const float iN0 = 1.f / N0, iN1 = 1.f / N1, iN2 = 1.f / N2, iN3 = 1.f / N3,
                iN4 = 1.f / N4, iN5 = 1.f / N5, i8 = 1.f / 8.f;

    zero_kernel<<<56, 256, 0, stream>>>(stats, 14 * 1024);

    // ---- mlp1 raw -> bufA; stats; in-place normalize
    mlp1_kernel<<<N0 / 256, 256, 0, stream>>>(x, w_mlp1, bufA, N0);
    stats4_kernel<<<768, 256, 0, stream>>>((const float4*)bufA, N0 * 4, 16, 4, st(0));
    norm0_kernel<<<N0 * 4 / 256, 256, 0, stream>>>(
        (float4*)bufA, N0 * 4, st(0), g_mlp1, b_mlp1, iN0);

    // ---- level 0: conv1 16->32 (PREF, RT=1, fused stats), down1, pool1
    convd_kernel<16, 32, 32, 1, 2048, 64, 256, 2, 27, true, true>
        <<<2048, 256, 0, stream>>>(bufA, nbr[0], w_c[0], bufB, st(1));
    down3_kernel<16, 32, 32, 2, 256>
        <<<1024, 256, 0, stream>>>(bufA, bufB, w_d[0], bufC,
                                   st(1), g_c[0], b_c[0], iN0, st(2));
    pool2_kernel<32, 256><<<N1 * 8 / 256, 256, 0, stream>>>(
        bufC, pool[0], st(2), g_d[0], b_d[0], iN0, bufA, N1);

    // ---- level 1: conv2 32->48 (PREF, ks=3, KT=9)
    convd_kernel<32, 48, 48, 1, 1024, 32, 192, 2, 9, false, true>
        <<<3072, 192, 0, stream>>>(bufA, nbr[1], w_c[1], bufB, nullptr);
    reducek_kernel<48, 3><<<1024, 192, 0, stream>>>(
        (const float4*)bufB, (float4*)bufB, N1 * 12, st(3));
    down3_kernel<32, 48, 48, 2, 192>
        <<<512, 192, 0, stream>>>(bufA, bufB, w_d[1], bufC,
                                  st(3), g_c[1], b_c[1], iN1, st(4));
    pool2_kernel<48, 192><<<N2 * 12 / 192, 192, 0, stream>>>(
        bufC, pool[1], st(4), g_d[1], b_d[1], iN1, bufA, N2);

    // ---- level 2: conv3 48->96 (NCOT=2, ks=3, KT=9)
    convd_kernel<48, 96, 48, 2, 256, 32, 192, 2, 9, false, false>
        <<<1536, 192, 0, stream>>>(bufA, nbr[2], w_c[2], bufB, nullptr);
    reducek_kernel<96, 3><<<1024, 192, 0, stream>>>(
        (const float4*)bufB, (float4*)bufB, N2 * 24, st(5));
    down3_kernel<48, 96, 96, 2, 192>
        <<<256, 192, 0, stream>>>(bufA, bufB, w_d[2], bufC,
                                  st(5), g_c[2], b_c[2], iN2, st(6));
    pool2_kernel<96, 192><<<N3 * 24 / 192, 192, 0, stream>>>(
        bufC, pool[2], st(6), g_d[2], b_d[2], iN2, bufA, N3);

    // ---- level 3: conv4 96->128 (NCOT=2, ks=9, KT=3)
    convd_kernel<96, 128, 64, 2, 64, 32, 256, 2, 3, false, false>
        <<<1152, 256, 0, stream>>>(bufA, nbr[3], w_c[3], bufB, nullptr);
    reducek_kernel<128, 9><<<256, 256, 0, stream>>>(
        (const float4*)bufB, (float4*)bufB, N3 * 32, st(7));
    down3_kernel<96, 128, 128, 2, 256>
        <<<64, 256, 0, stream>>>(bufA, bufB, w_d[3], bufC,
                                 st(7), g_c[3], b_c[3], iN3, st(8));
    pool2_kernel<128, 256><<<N4 * 32 / 256, 256, 0, stream>>>(
        bufC, pool[3], st(8), g_d[3], b_d[3], iN3, bufA, N4);

    // ---- level 4: conv5 128->256 (NCOT=4, ks=9, KT=3)
    convd_kernel<128, 256, 64, 4, 16, 32, 256, 2, 3, false, false>
        <<<576, 256, 0, stream>>>(bufA, nbr[4], w_c[4], bufB, nullptr);
    reducek_kernel<256, 9><<<128, 256, 0, stream>>>(
        (const float4*)bufB, (float4*)bufB, N4 * 64, st(9));
    down3_kernel<128, 256, 256, 2, 256>
        <<<32, 256, 0, stream>>>(bufA, bufB, w_d[4], bufC,
                                 st(9), g_c[4], b_c[4], iN4, st(10));
    pool2_kernel<256, 256><<<N5 * 64 / 256, 256, 0, stream>>>(
        bufC, pool[4], st(10), g_d[4], b_d[4], iN4, bufA, N5);

    // ---- conv6 256->512 (NCOT=8, ks=9, KT=3)
    convd_kernel<256, 512, 64, 8, 8, 32, 256, 2, 3, false, false>
        <<<576, 256, 0, stream>>>(bufA, nbr[5], w_c[5], bufB, nullptr);
    reducek_kernel<512, 9><<<128, 256, 0, stream>>>(
        (const float4*)bufB, (float4*)bufB, N5 * 128, st(11));

    // ---- segment pooling (applies conv6 BN) -> z in bufC
    segpool2_kernel<<<8, 512, 0, stream>>>(bufB, st(11), g_c[5], b_c[5], iN5, bufC);

    // ---- f1
    zero_kernel<<<16, 256, 0, stream>>>(bufB, 4096);
    fc_kernel<1024, 512, 4, false><<<dim3(8, 4), 256, 0, stream>>>(
        bufC, w_f1, nullptr, nullptr, nullptr, 0.f, bufB);
    stats4_kernel<<<4, 256, 0, stream>>>((const float4*)bufB, 1024, 512, 128, st(12));

    // ---- f2
    zero_kernel<<<8, 256, 0, stream>>>(bufB + 4096, 2048);
    fc_kernel<512, 256, 4, true><<<dim3(4, 4), 256, 0, stream>>>(
        bufB, w_f2, st(12), g_f1, b_f1, i8, bufB + 4096);
    stats4_kernel<<<2, 256, 0, stream>>>(
        (const float4*)(bufB + 4096), 512, 256, 64, st(13));

    // ---- f3
    f3n_kernel<<<1, 256, 0, stream>>>(bufB + 4096, w_f3, bias_f3,
                                      st(13), g_f2, b_f2, i8, out);
}

// Round 8
// 1172.666 us; speedup vs baseline: 1.2748x; 1.2748x over previous
//
#include <hip/hip_runtime.h>
#include <math.h>

#define BN_EPS 1e-5f

// ---------------------------------------------------------------------------
// Round 8: round-5 proven base + spill-free PREF conv1/conv2 (RT=1, static
// register buffers, doubled grids), norm0 pre-pass, mlp1-fused stats.
// ---------------------------------------------------------------------------

__device__ __forceinline__ void fma4(float s, const float4& w, float4& a) {
    a.x = fmaf(s, w.x, a.x);
    a.y = fmaf(s, w.y, a.y);
    a.z = fmaf(s, w.z, a.z);
    a.w = fmaf(s, w.w, a.w);
}

__device__ __forceinline__ float nlr(float x, float sc, float sh) {
    float t = fmaf(x, sc, sh);
    return fmaxf(t, 0.01f * t);
}

__device__ __forceinline__ void bn_coef(const float* __restrict__ sums,
                                        const float* __restrict__ g,
                                        const float* __restrict__ b,
                                        int C, int c, float inv_n,
                                        float& sc, float& sh) {
    float mean = sums[c] * inv_n;
    float var = fmaxf(fmaf(-mean, mean, sums[C + c] * inv_n), 0.f);
    sc = g[c] * rsqrtf(var + BN_EPS);
    sh = fmaf(-mean, sc, b[c]);
}

__global__ void zero_kernel(float* __restrict__ p, int n) {
    int i = blockIdx.x * blockDim.x + threadIdx.x;
    if (i < n) p[i] = 0.f;
}

// mlp1 with fused per-channel stats (wave shuffle reduce -> LDS -> global)
__global__ __launch_bounds__(256) void mlp1s_kernel(
    const float* __restrict__ x, const float* __restrict__ w,
    float* __restrict__ out, int N, float* __restrict__ sums) {
    __shared__ float ls[32];
    int tid = threadIdx.x;
    if (tid < 32) ls[tid] = 0.f;
    __syncthreads();
    int n = blockIdx.x * blockDim.x + tid;
    float o[16];
    if (n < N) {
        float x0 = x[n * 3], x1 = x[n * 3 + 1], x2 = x[n * 3 + 2];
        #pragma unroll
        for (int c = 0; c < 16; c++)
            o[c] = fmaf(x0, w[c], fmaf(x1, w[16 + c], x2 * w[32 + c]));
        #pragma unroll
        for (int c4 = 0; c4 < 4; c4++)
            *reinterpret_cast<float4*>(out + n * 16 + c4 * 4) =
                make_float4(o[c4 * 4], o[c4 * 4 + 1], o[c4 * 4 + 2], o[c4 * 4 + 3]);
    } else {
        #pragma unroll
        for (int c = 0; c < 16; c++) o[c] = 0.f;
    }
    float q[16];
    #pragma unroll
    for (int c = 0; c < 16; c++) q[c] = o[c] * o[c];
    #pragma unroll
    for (int m = 1; m < 64; m <<= 1) {
        #pragma unroll
        for (int c = 0; c < 16; c++) {
            o[c] += __shfl_xor(o[c], m, 64);
            q[c] += __shfl_xor(q[c], m, 64);
        }
    }
    if ((tid & 63) == 0) {
        #pragma unroll
        for (int c = 0; c < 16; c++) {
            atomicAdd(&ls[c], o[c]);
            atomicAdd(&ls[16 + c], q[c]);
        }
    }
    __syncthreads();
    if (tid < 32) atomicAdd(&sums[tid], ls[tid]);
}

// in-place BN+lrelu on fp32 y0 (C=16); one float4 per thread
__global__ void norm0_kernel(float4* __restrict__ y, int total4,
                             const float* __restrict__ sums, const float* __restrict__ g,
                             const float* __restrict__ b, float inv_n) {
    __shared__ float lsc[16], lsh[16];
    int tid = threadIdx.x;
    if (tid < 16) {
        float sc, sh;
        bn_coef(sums, g, b, 16, tid, inv_n, sc, sh);
        lsc[tid] = sc;
        lsh[tid] = sh;
    }
    __syncthreads();
    int i = blockIdx.x * blockDim.x + tid;
    if (i >= total4) return;
    int cb = (i & 3) * 4;
    float4 v = y[i];
    v.x = nlr(v.x, lsc[cb + 0], lsh[cb + 0]);
    v.y = nlr(v.y, lsc[cb + 1], lsh[cb + 1]);
    v.z = nlr(v.z, lsc[cb + 2], lsh[cb + 2]);
    v.w = nlr(v.w, lsc[cb + 3], lsh[cb + 3]);
    y[i] = v;
}

// per-channel sum & sumsq, float4; requires blockDim % C4 == 0
__global__ void stats4_kernel(const float4* __restrict__ x, int total4, int C, int C4,
                              float* __restrict__ sums) {
    __shared__ float ls[1024];
    int tid = threadIdx.x;
    for (int j = tid; j < 2 * C; j += blockDim.x) ls[j] = 0.f;
    __syncthreads();
    int stride = gridDim.x * blockDim.x;
    int i = blockIdx.x * blockDim.x + tid;
    int c4 = i % C4;
    float4 s = make_float4(0.f, 0.f, 0.f, 0.f);
    float4 q = make_float4(0.f, 0.f, 0.f, 0.f);
    for (; i < total4; i += stride) {
        float4 v = x[i];
        s.x += v.x; s.y += v.y; s.z += v.z; s.w += v.w;
        q.x = fmaf(v.x, v.x, q.x); q.y = fmaf(v.y, v.y, q.y);
        q.z = fmaf(v.z, v.z, q.z); q.w = fmaf(v.w, v.w, q.w);
    }
    int cb = c4 * 4;
    atomicAdd(&ls[cb + 0], s.x); atomicAdd(&ls[cb + 1], s.y);
    atomicAdd(&ls[cb + 2], s.z); atomicAdd(&ls[cb + 3], s.w);
    atomicAdd(&ls[C + cb + 0], q.x); atomicAdd(&ls[C + cb + 1], q.y);
    atomicAdd(&ls[C + cb + 2], q.z); atomicAdd(&ls[C + cb + 3], q.w);
    __syncthreads();
    for (int j = tid; j < 2 * C; j += blockDim.x) atomicAdd(&sums[j], ls[j]);
}

// reduce KS k-split partial slices + fused stats; out aliases slice 0
template <int C, int KS>
__global__ void reducek_kernel(const float4* __restrict__ in, float4* __restrict__ out,
                               int total4, float* __restrict__ sums) {
    __shared__ float ls[1024];
    constexpr int C4 = C / 4;
    int tid = threadIdx.x;
    for (int j = tid; j < 2 * C; j += blockDim.x) ls[j] = 0.f;
    __syncthreads();
    int stride = gridDim.x * blockDim.x;
    int i = blockIdx.x * blockDim.x + tid;
    int c4 = i % C4;
    float4 s = make_float4(0.f, 0.f, 0.f, 0.f);
    float4 q = make_float4(0.f, 0.f, 0.f, 0.f);
    for (; i < total4; i += stride) {
        float4 v = make_float4(0.f, 0.f, 0.f, 0.f);
        #pragma unroll
        for (int p = 0; p < KS; p++) {
            float4 t = in[(size_t)p * total4 + i];
            v.x += t.x; v.y += t.y; v.z += t.z; v.w += t.w;
        }
        out[i] = v;
        s.x += v.x; s.y += v.y; s.z += v.z; s.w += v.w;
        q.x = fmaf(v.x, v.x, q.x); q.y = fmaf(v.y, v.y, q.y);
        q.z = fmaf(v.z, v.z, q.z); q.w = fmaf(v.w, v.w, q.w);
    }
    int cb = c4 * 4;
    atomicAdd(&ls[cb + 0], s.x); atomicAdd(&ls[cb + 1], s.y);
    atomicAdd(&ls[cb + 2], s.z); atomicAdd(&ls[cb + 3], s.w);
    atomicAdd(&ls[C + cb + 0], q.x); atomicAdd(&ls[C + cb + 1], q.y);
    atomicAdd(&ls[C + cb + 2], q.z); atomicAdd(&ls[C + cb + 3], q.w);
    __syncthreads();
    for (int j = tid; j < 2 * C; j += blockDim.x) atomicAdd(&sums[j], ls[j]);
}

// ---------------------------------------------------------------------------
// Direct sparse conv, fp32 normalized input.  grid = NCOT*MT*KS.
// PREF: named double-buffered y lookahead (all register arrays statically
// indexed via unrolled loops -- no scratch).
// ---------------------------------------------------------------------------
template <int CIN, int COUT, int CO_TILE, int NCOT, int MT, int TM, int NTHR,
          int NQ, int KT, bool STATS, bool PREF>
__global__ __launch_bounds__(NTHR) void convd_kernel(
    const float* __restrict__ y, const int* __restrict__ nbr,
    const float* __restrict__ w, float* __restrict__ out,
    float* __restrict__ s_out) {
    constexpr int CQT = CO_TILE / (4 * NQ);
    constexpr int MGRP = NTHR / CQT;
    constexpr int RT = TM / MGRP;
    constexpr int C4N = CIN / 4;
    static_assert(MGRP * RT == TM, "tile mismatch");
    static_assert(MGRP * CQT == NTHR, "thread mismatch");

    __shared__ float sred[STATS ? 2 * CO_TILE : 1];

    const int tid = threadIdx.x;
    const int bid = blockIdx.x;
    const int cot = bid % NCOT;
    const int rest = bid / NCOT;
    const int mt = rest % MT;
    const int ks = rest / MT;
    const int m0 = mt * TM;
    const int cobase = cot * CO_TILE;
    const int k0 = ks * KT;
    const int cq = tid % CQT;
    const int mg = tid / CQT;

    int mrow[RT];
    #pragma unroll
    for (int r = 0; r < RT; r++) mrow[r] = m0 + mg + r * MGRP;

    float4 acc[RT][NQ];
    #pragma unroll
    for (int r = 0; r < RT; r++)
        #pragma unroll
        for (int q = 0; q < NQ; q++) acc[r][q] = make_float4(0.f, 0.f, 0.f, 0.f);

    auto ldidx = [&](int k, int (&rr)[RT]) {
        #pragma unroll
        for (int r = 0; r < RT; r++) rr[r] = nbr[(size_t)mrow[r] * 27 + k];
    };

    if constexpr (PREF) {
        auto ldy = [&](const int (&rr)[RT], float4 (&yv)[RT][C4N]) {
            #pragma unroll
            for (int r = 0; r < RT; r++)
                #pragma unroll
                for (int c4 = 0; c4 < C4N; c4++)
                    yv[r][c4] = *reinterpret_cast<const float4*>(
                        y + (size_t)rr[r] * CIN + c4 * 4);
        };
        auto fmak = [&](int k, const float4 (&yv)[RT][C4N]) {
            const float* wk = w + (size_t)k * CIN * COUT + cobase + cq * (4 * NQ);
            #pragma unroll
            for (int c4 = 0; c4 < C4N; c4++) {
                #pragma unroll
                for (int jj = 0; jj < 4; jj++) {
                    #pragma unroll
                    for (int q = 0; q < NQ; q++) {
                        float4 wv = *reinterpret_cast<const float4*>(
                            wk + (size_t)(c4 * 4 + jj) * COUT + q * 4);
                        #pragma unroll
                        for (int r = 0; r < RT; r++) {
                            float e = jj == 0 ? yv[r][c4].x : jj == 1 ? yv[r][c4].y
                                     : jj == 2 ? yv[r][c4].z : yv[r][c4].w;
                            fma4(e, wv, acc[r][q]);
                        }
                    }
                }
            }
        };
        int ra[RT], rb[RT];
        float4 ya[RT][C4N], yb[RT][C4N];
        ldidx(k0, ra);
        ldy(ra, ya);
        int kk = 0;
        for (; kk + 2 <= KT; kk += 2) {
            ldidx(k0 + kk + 1, rb);
            ldy(rb, yb);
            fmak(k0 + kk, ya);
            if (kk + 2 < KT) {
                ldidx(k0 + kk + 2, ra);
                ldy(ra, ya);
            }
            fmak(k0 + kk + 1, yb);
        }
        if (KT & 1) fmak(k0 + KT - 1, ya);
    } else {
        int rows[RT];
        ldidx(k0, rows);
        for (int kk = k0; kk < k0 + KT; kk++) {
            int rnext[RT];
            if (kk + 1 < k0 + KT) ldidx(kk + 1, rnext);
            const float* wk = w + (size_t)kk * CIN * COUT + cobase + cq * (4 * NQ);
            #pragma unroll 4
            for (int c4 = 0; c4 < C4N; c4++) {
                float4 yv[RT];
                #pragma unroll
                for (int r = 0; r < RT; r++)
                    yv[r] = *reinterpret_cast<const float4*>(
                        y + (size_t)rows[r] * CIN + c4 * 4);
                #pragma unroll
                for (int jj = 0; jj < 4; jj++) {
                    #pragma unroll
                    for (int q = 0; q < NQ; q++) {
                        float4 wv = *reinterpret_cast<const float4*>(
                            wk + (size_t)(c4 * 4 + jj) * COUT + q * 4);
                        #pragma unroll
                        for (int r = 0; r < RT; r++) {
                            float e = jj == 0 ? yv[r].x : jj == 1 ? yv[r].y
                                     : jj == 2 ? yv[r].z : yv[r].w;
                            fma4(e, wv, acc[r][q]);
                        }
                    }
                }
            }
            #pragma unroll
            for (int r = 0; r < RT; r++) rows[r] = rnext[r];
        }
    }

    float* outp = out + (size_t)ks * MT * TM * COUT;
    #pragma unroll
    for (int r = 0; r < RT; r++)
        #pragma unroll
        for (int q = 0; q < NQ; q++)
            *reinterpret_cast<float4*>(
                outp + (size_t)mrow[r] * COUT + cobase + cq * (4 * NQ) + q * 4) =
                acc[r][q];

    if constexpr (STATS) {
        for (int j = tid; j < 2 * CO_TILE; j += NTHR) sred[j] = 0.f;
        __syncthreads();
        #pragma unroll
        for (int q = 0; q < NQ; q++) {
            float4 s = make_float4(0.f, 0.f, 0.f, 0.f);
            float4 qq = make_float4(0.f, 0.f, 0.f, 0.f);
            #pragma unroll
            for (int r = 0; r < RT; r++) {
                float4 v = acc[r][q];
                s.x += v.x; s.y += v.y; s.z += v.z; s.w += v.w;
                qq.x = fmaf(v.x, v.x, qq.x); qq.y = fmaf(v.y, v.y, qq.y);
                qq.z = fmaf(v.z, v.z, qq.z); qq.w = fmaf(v.w, v.w, qq.w);
            }
            int cb = cq * (4 * NQ) + q * 4;
            atomicAdd(&sred[cb + 0], s.x); atomicAdd(&sred[cb + 1], s.y);
            atomicAdd(&sred[cb + 2], s.z); atomicAdd(&sred[cb + 3], s.w);
            atomicAdd(&sred[CO_TILE + cb + 0], qq.x);
            atomicAdd(&sred[CO_TILE + cb + 1], qq.y);
            atomicAdd(&sred[CO_TILE + cb + 2], qq.z);
            atomicAdd(&sred[CO_TILE + cb + 3], qq.w);
        }
        __syncthreads();
        for (int j = tid; j < CO_TILE; j += NTHR) {
            atomicAdd(&s_out[cobase + j], sred[j]);
            atomicAdd(&s_out[COUT + cobase + j], sred[CO_TILE + j]);
        }
    }
}

// ---------------------------------------------------------------------------
// down (concat + 1x1): in1 = normalized y, in2 = raw conv out (inline norm).
// Fused output stats.
// ---------------------------------------------------------------------------
template <int C1, int C2, int COUT, int NQ, int NTHR>
__global__ __launch_bounds__(NTHR) void down3_kernel(
    const float* __restrict__ in1, const float* __restrict__ in2,
    const float* __restrict__ w, float* __restrict__ out,
    const float* __restrict__ s2, const float* __restrict__ g2,
    const float* __restrict__ b2, float inv2,
    float* __restrict__ s_out) {
    constexpr int CQT = COUT / (4 * NQ);
    constexpr int PAIRS = NTHR / CQT;
    __shared__ __align__(16) float n2c[C2], n2h[C2];
    __shared__ float sred[2 * COUT];

    const int tid = threadIdx.x;
    for (int c = tid; c < C2; c += NTHR) {
        float sc, sh;
        bn_coef(s2, g2, b2, C2, c, inv2, sc, sh);
        n2c[c] = sc; n2h[c] = sh;
    }
    for (int j = tid; j < 2 * COUT; j += NTHR) sred[j] = 0.f;
    __syncthreads();

    const int cq = tid % CQT;
    const int pr = tid / CQT;
    const int n0 = (blockIdx.x * PAIRS + pr) * 2;

    float4 acc[2][NQ];
    #pragma unroll
    for (int r = 0; r < 2; r++)
        #pragma unroll
        for (int q = 0; q < NQ; q++) acc[r][q] = make_float4(0.f, 0.f, 0.f, 0.f);

    const float* w1 = w + cq * (4 * NQ);
    #pragma unroll 8
    for (int ci4 = 0; ci4 < C1 / 4; ci4++) {
        float4 a0 = *reinterpret_cast<const float4*>(in1 + (size_t)n0 * C1 + ci4 * 4);
        float4 a1 = *reinterpret_cast<const float4*>(in1 + (size_t)(n0 + 1) * C1 + ci4 * 4);
        #pragma unroll
        for (int jj = 0; jj < 4; jj++) {
            const float* wp = w1 + (size_t)(ci4 * 4 + jj) * COUT;
            float e0 = jj == 0 ? a0.x : jj == 1 ? a0.y : jj == 2 ? a0.z : a0.w;
            float e1 = jj == 0 ? a1.x : jj == 1 ? a1.y : jj == 2 ? a1.z : a1.w;
            #pragma unroll
            for (int q = 0; q < NQ; q++) {
                float4 wv = *reinterpret_cast<const float4*>(wp + q * 4);
                fma4(e0, wv, acc[0][q]);
                fma4(e1, wv, acc[1][q]);
            }
        }
    }
    const float* w2 = w + (size_t)C1 * COUT + cq * (4 * NQ);
    #pragma unroll 8
    for (int ci4 = 0; ci4 < C2 / 4; ci4++) {
        float4 a0 = *reinterpret_cast<const float4*>(in2 + (size_t)n0 * C2 + ci4 * 4);
        float4 a1 = *reinterpret_cast<const float4*>(in2 + (size_t)(n0 + 1) * C2 + ci4 * 4);
        float4 sc = *reinterpret_cast<const float4*>(&n2c[ci4 * 4]);
        float4 sh = *reinterpret_cast<const float4*>(&n2h[ci4 * 4]);
        a0.x = nlr(a0.x, sc.x, sh.x); a0.y = nlr(a0.y, sc.y, sh.y);
        a0.z = nlr(a0.z, sc.z, sh.z); a0.w = nlr(a0.w, sc.w, sh.w);
        a1.x = nlr(a1.x, sc.x, sh.x); a1.y = nlr(a1.y, sc.y, sh.y);
        a1.z = nlr(a1.z, sc.z, sh.z); a1.w = nlr(a1.w, sc.w, sh.w);
        #pragma unroll
        for (int jj = 0; jj < 4; jj++) {
            const float* wp = w2 + (size_t)(ci4 * 4 + jj) * COUT;
            float e0 = jj == 0 ? a0.x : jj == 1 ? a0.y : jj == 2 ? a0.z : a0.w;
            float e1 = jj == 0 ? a1.x : jj == 1 ? a1.y : jj == 2 ? a1.z : a1.w;
            #pragma unroll
            for (int q = 0; q < NQ; q++) {
                float4 wv = *reinterpret_cast<const float4*>(wp + q * 4);
                fma4(e0, wv, acc[0][q]);
                fma4(e1, wv, acc[1][q]);
            }
        }
    }
    #pragma unroll
    for (int r = 0; r < 2; r++)
        #pragma unroll
        for (int q = 0; q < NQ; q++)
            *reinterpret_cast<float4*>(out + (size_t)(n0 + r) * COUT + cq * (4 * NQ) + q * 4) =
                acc[r][q];

    #pragma unroll
    for (int q = 0; q < NQ; q++) {
        float4 s = make_float4(0.f, 0.f, 0.f, 0.f);
        float4 qq = make_float4(0.f, 0.f, 0.f, 0.f);
        #pragma unroll
        for (int r = 0; r < 2; r++) {
            float4 v = acc[r][q];
            s.x += v.x; s.y += v.y; s.z += v.z; s.w += v.w;
            qq.x = fmaf(v.x, v.x, qq.x); qq.y = fmaf(v.y, v.y, qq.y);
            qq.z = fmaf(v.z, v.z, qq.z); qq.w = fmaf(v.w, v.w, qq.w);
        }
        int cb = cq * (4 * NQ) + q * 4;
        atomicAdd(&sred[cb + 0], s.x); atomicAdd(&sred[cb + 1], s.y);
        atomicAdd(&sred[cb + 2], s.z); atomicAdd(&sred[cb + 3], s.w);
        atomicAdd(&sred[COUT + cb + 0], qq.x);
        atomicAdd(&sred[COUT + cb + 1], qq.y);
        atomicAdd(&sred[COUT + cb + 2], qq.z);
        atomicAdd(&sred[COUT + cb + 3], qq.w);
    }
    __syncthreads();
    for (int j = tid; j < COUT; j += NTHR) {
        atomicAdd(&s_out[j], sred[j]);
        atomicAdd(&s_out[COUT + j], sred[COUT + j]);
    }
}

// ---------------------------------------------------------------------------
// pool: min/max over 27 raw rows, BN+lrelu by scale sign -> normalized y
// ---------------------------------------------------------------------------
template <int C, int NTHR>
__global__ __launch_bounds__(NTHR) void pool2_kernel(
    const float* __restrict__ draw, const int* __restrict__ pmap,
    const float* __restrict__ sums, const float* __restrict__ g,
    const float* __restrict__ b, float inv_n,
    float* __restrict__ yout, int Nout) {
    constexpr int C4 = C / 4;
    int i = blockIdx.x * NTHR + threadIdx.x;
    if (i >= Nout * C4) return;
    int n = i / C4, c4 = i % C4;
    float sc[4], sh[4];
    #pragma unroll
    for (int j = 0; j < 4; j++) bn_coef(sums, g, b, C, c4 * 4 + j, inv_n, sc[j], sh[j]);
    const int* pm = pmap + n * 27;
    float4 mn = make_float4(INFINITY, INFINITY, INFINITY, INFINITY);
    float4 mx = make_float4(-INFINITY, -INFINITY, -INFINITY, -INFINITY);
    #pragma unroll 9
    for (int k = 0; k < 27; k++) {
        int row = pm[k];
        float4 v = *reinterpret_cast<const float4*>(draw + (size_t)row * C + c4 * 4);
        mn.x = fminf(mn.x, v.x); mn.y = fminf(mn.y, v.y);
        mn.z = fminf(mn.z, v.z); mn.w = fminf(mn.w, v.w);
        mx.x = fmaxf(mx.x, v.x); mx.y = fmaxf(mx.y, v.y);
        mx.z = fmaxf(mx.z, v.z); mx.w = fmaxf(mx.w, v.w);
    }
    float4 o;
    o.x = nlr(sc[0] >= 0.f ? mx.x : mn.x, sc[0], sh[0]);
    o.y = nlr(sc[1] >= 0.f ? mx.y : mn.y, sc[1], sh[1]);
    o.z = nlr(sc[2] >= 0.f ? mx.z : mn.z, sc[2], sh[2]);
    o.w = nlr(sc[3] >= 0.f ? mx.w : mn.w, sc[3], sh[3]);
    *reinterpret_cast<float4*>(yout + (size_t)n * C + c4 * 4) = o;
}

__global__ void segpool2_kernel(const float* __restrict__ y,
                                const float* __restrict__ sums,
                                const float* __restrict__ g, const float* __restrict__ b,
                                float inv_n, float* __restrict__ z) {
    int bi = blockIdx.x;
    int c = threadIdx.x;  // 512
    float sc, sh;
    bn_coef(sums, g, b, 512, c, inv_n, sc, sh);
    float mn = INFINITY, mx = -INFINITY, sm = 0.f;
    for (int r = 0; r < 32; r++) {
        float v = y[(size_t)(bi * 32 + r) * 512 + c];
        mn = fminf(mn, v);
        mx = fmaxf(mx, v);
        sm += nlr(v, sc, sh);
    }
    z[bi * 1024 + c] = nlr(sc >= 0.f ? mx : mn, sc, sh);
    z[bi * 1024 + 512 + c] = sm * (1.f / 32.f);
}

// FC (M=8): grid (COUT/64, KSPLIT); optional input normalization at staging
template <int K, int COUT, int KSPLIT, bool NORM>
__global__ __launch_bounds__(256) void fc_kernel(
    const float* __restrict__ z, const float* __restrict__ w,
    const float* __restrict__ ns, const float* __restrict__ ng,
    const float* __restrict__ nb, float inv_n,
    float* __restrict__ out) {
    constexpr int KC = K / KSPLIT;
    constexpr int KG = KC / 16;
    __shared__ __align__(16) float zt[KC * 8];
    __shared__ float red[16 * 520];

    const int cobase = blockIdx.x * 64;
    const int kc0 = blockIdx.y * KC;
    const int tid = threadIdx.x;
    const int coq = tid & 15;
    const int kg = tid >> 4;

    for (int idx = tid; idx < 8 * (KC / 4); idx += 256) {
        int n = idx / (KC / 4);
        int kq = idx - n * (KC / 4);
        float4 v = *reinterpret_cast<const float4*>(z + (size_t)n * K + kc0 + kq * 4);
        if constexpr (NORM) {
            #pragma unroll
            for (int j = 0; j < 4; j++) {
                float sc, sh;
                bn_coef(ns, ng, nb, K, kc0 + kq * 4 + j, inv_n, sc, sh);
                float* pv = j == 0 ? &v.x : j == 1 ? &v.y : j == 2 ? &v.z : &v.w;
                *pv = nlr(*pv, sc, sh);
            }
        }
        zt[(kq * 4 + 0) * 8 + n] = v.x;
        zt[(kq * 4 + 1) * 8 + n] = v.y;
        zt[(kq * 4 + 2) * 8 + n] = v.z;
        zt[(kq * 4 + 3) * 8 + n] = v.w;
    }
    __syncthreads();

    float4 acc[8];
    #pragma unroll
    for (int n = 0; n < 8; n++) acc[n] = make_float4(0.f, 0.f, 0.f, 0.f);
    for (int ki = 0; ki < KG; ki++) {
        int k = kg * KG + ki;
        float4 wv = *reinterpret_cast<const float4*>(
            w + (size_t)(kc0 + k) * COUT + cobase + coq * 4);
        float4 za = *reinterpret_cast<const float4*>(&zt[k * 8]);
        float4 zb = *reinterpret_cast<const float4*>(&zt[k * 8 + 4]);
        fma4(za.x, wv, acc[0]); fma4(za.y, wv, acc[1]);
        fma4(za.z, wv, acc[2]); fma4(za.w, wv, acc[3]);
        fma4(zb.x, wv, acc[4]); fma4(zb.y, wv, acc[5]);
        fma4(zb.z, wv, acc[6]); fma4(zb.w, wv, acc[7]);
    }
    #pragma unroll
    for (int n = 0; n < 8; n++) {
        red[kg * 520 + (coq * 4 + 0) * 8 + n] = acc[n].x;
        red[kg * 520 + (coq * 4 + 1) * 8 + n] = acc[n].y;
        red[kg * 520 + (coq * 4 + 2) * 8 + n] = acc[n].z;
        red[kg * 520 + (coq * 4 + 3) * 8 + n] = acc[n].w;
    }
    __syncthreads();
    for (int oi = tid; oi < 512; oi += 256) {
        int c = oi >> 3;
        int n = oi & 7;
        float s = 0.f;
        #pragma unroll
        for (int gg = 0; gg < 16; gg++) s += red[gg * 520 + c * 8 + n];
        float* op = out + (size_t)n * COUT + cobase + c;
        if (KSPLIT > 1) atomicAdd(op, s);
        else *op = s;
    }
}

__global__ void f3n_kernel(const float* __restrict__ in, const float* __restrict__ w,
                           const float* __restrict__ bias,
                           const float* __restrict__ sums, const float* __restrict__ g,
                           const float* __restrict__ b, float inv_n,
                           float* __restrict__ out) {
    __shared__ float zin[8 * 256];
    int tid = threadIdx.x;  // 256
    for (int idx = tid; idx < 2048; idx += 256) {
        int c = idx & 255;
        float sc, sh;
        bn_coef(sums, g, b, 256, c, inv_n, sc, sh);
        zin[idx] = nlr(in[idx], sc, sh);
    }
    __syncthreads();
    if (tid >= 160) return;
    int n = tid / 20, co = tid % 20;
    float acc = bias[co];
    for (int ci = 0; ci < 256; ci++)
        acc = fmaf(zin[n * 256 + ci], w[ci * 20 + co], acc);
    out[tid] = acc;
}

// ---------------------------------------------------------------------------

extern "C" void kernel_launch(void* const* d_in, const int* in_sizes, int n_in,
                              void* d_out, int out_size, void* d_ws, size_t ws_size,
                              hipStream_t stream) {
    (void)in_sizes; (void)n_in; (void)out_size; (void)ws_size;

    const int N0 = 131072, N1 = 32768, N2 = 8192, N3 = 2048, N4 = 512, N5 = 256;

    const float* x      = (const float*)d_in[0];
    const float* w_mlp1 = (const float*)d_in[1];
    const float* g_mlp1 = (const float*)d_in[2];
    const float* b_mlp1 = (const float*)d_in[3];
    const float* w_c[6]; const float* g_c[6]; const float* b_c[6];
    for (int i = 0; i < 6; i++) {
        w_c[i] = (const float*)d_in[4 + 3 * i];
        g_c[i] = (const float*)d_in[5 + 3 * i];
        b_c[i] = (const float*)d_in[6 + 3 * i];
    }
    const float* w_d[5]; const float* g_d[5]; const float* b_d[5];
    for (int i = 0; i < 5; i++) {
        w_d[i] = (const float*)d_in[22 + 3 * i];
        g_d[i] = (const float*)d_in[23 + 3 * i];
        b_d[i] = (const float*)d_in[24 + 3 * i];
    }
    const float* w_f1 = (const float*)d_in[37];
    const float* g_f1 = (const float*)d_in[38];
    const float* b_f1 = (const float*)d_in[39];
    const float* w_f2 = (const float*)d_in[40];
    const float* g_f2 = (const float*)d_in[41];
    const float* b_f2 = (const float*)d_in[42];
    const float* w_f3 = (const float*)d_in[43];
    const float* bias_f3 = (const float*)d_in[44];
    const int* nbr[6];
    for (int i = 0; i < 6; i++) nbr[i] = (const int*)d_in[45 + i];
    const int* pool[5];
    for (int i = 0; i < 5; i++) pool[i] = (const int*)d_in[51 + i];

    float* ws    = (float*)d_ws;
    float* bufA  = ws;                    // normalized y levels
    float* bufB  = bufA + 2097152;        // conv finals + partial arena
    float* bufC  = bufB + 4194304;        // down raw / z / partial spill
    float* stats = bufC + 4194304;
    float* out = (float*)d_out;

    auto st = [&](int slot) { return stats + slot * 1024; };

    const float iN0 = 1.f / N0, iN1 = 1.f / N1, iN2 = 1.f / N2, iN3 = 1.f / N3,
                iN4 = 1.f / N4, iN5 = 1.f / N5, i8 = 1.f / 8.f;

    zero_kernel<<<56, 256, 0, stream>>>(stats, 14 * 1024);

    // ---- mlp1 raw -> bufA with fused stats; in-place normalize
    mlp1s_kernel<<<N0 / 256, 256, 0, stream>>>(x, w_mlp1, bufA, N0, st(0));
    norm0_kernel<<<N0 * 4 / 256, 256, 0, stream>>>(
        (float4*)bufA, N0 * 4, st(0), g_mlp1, b_mlp1, iN0);

    // ---- level 0: conv1 16->32 (PREF RT=1, 2048 blocks, fused stats)
    convd_kernel<16, 32, 32, 1, 2048, 64, 256, 2, 27, true, true>
        <<<2048, 256, 0, stream>>>(bufA, nbr[0], w_c[0], bufB, st(1));
    down3_kernel<16, 32, 32, 2, 256>
        <<<1024, 256, 0, stream>>>(bufA, bufB, w_d[0], bufC,
                                   st(1), g_c[0], b_c[0], iN0, st(2));
    pool2_kernel<32, 256><<<N1 * 8 / 256, 256, 0, stream>>>(
        bufC, pool[0], st(2), g_d[0], b_d[0], iN0, bufA, N1);

    // ---- level 1: conv2 32->48 (PREF RT=1, ks=3 KT=9, 3072 blocks)
    convd_kernel<32, 48, 48, 1, 1024, 32, 192, 2, 9, false, true>
        <<<3072, 192, 0, stream>>>(bufA, nbr[1], w_c[1], bufB, nullptr);
    reducek_kernel<48, 3><<<1024, 192, 0, stream>>>(
        (const float4*)bufB, (float4*)bufB, N1 * 12, st(3));
    down3_kernel<32, 48, 48, 2, 192>
        <<<512, 192, 0, stream>>>(bufA, bufB, w_d[1], bufC,
                                  st(3), g_c[1], b_c[1], iN1, st(4));
    pool2_kernel<48, 192><<<N2 * 12 / 192, 192, 0, stream>>>(
        bufC, pool[1], st(4), g_d[1], b_d[1], iN1, bufA, N2);

    // ---- level 2: conv3 48->96 (round-5 proven: NCOT=2, ks=9, KT=3)
    convd_kernel<48, 96, 48, 2, 128, 64, 192, 2, 3, false, false>
        <<<2304, 192, 0, stream>>>(bufA, nbr[2], w_c[2], bufB, nullptr);
    reducek_kernel<96, 9><<<1024, 192, 0, stream>>>(
        (const float4*)bufB, (float4*)bufB, N2 * 24, st(5));
    down3_kernel<48, 96, 96, 2, 192>
        <<<256, 192, 0, stream>>>(bufA, bufB, w_d[2], bufC,
                                  st(5), g_c[2], b_c[2], iN2, st(6));
    pool2_kernel<96, 192><<<N3 * 24 / 192, 192, 0, stream>>>(
        bufC, pool[2], st(6), g_d[2], b_d[2], iN2, bufA, N3);

    // ---- level 3: conv4 96->128 (round-5: NCOT=2, ks=27, KT=1)
    convd_kernel<96, 128, 64, 2, 32, 64, 256, 2, 1, false, false>
        <<<1728, 256, 0, stream>>>(bufA, nbr[3], w_c[3], bufB, nullptr);
    reducek_kernel<128, 27><<<256, 256, 0, stream>>>(
        (const float4*)bufB, (float4*)bufB, N3 * 32, st(7));
    down3_kernel<96, 128, 128, 2, 256>
        <<<64, 256, 0, stream>>>(bufA, bufB, w_d[3], bufC,
                                 st(7), g_c[3], b_c[3], iN3, st(8));
    pool2_kernel<128, 256><<<N4 * 32 / 256, 256, 0, stream>>>(
        bufC, pool[3], st(8), g_d[3], b_d[3], iN3, bufA, N4);

    // ---- level 4: conv5 128->256 (round-5: NCOT=4, ks=27)
    convd_kernel<128, 256, 64, 4, 8, 64, 256, 2, 1, false, false>
        <<<864, 256, 0, stream>>>(bufA, nbr[4], w_c[4], bufB, nullptr);
    reducek_kernel<256, 27><<<128, 256, 0, stream>>>(
        (const float4*)bufB, (float4*)bufB, N4 * 64, st(9));
    down3_kernel<128, 256, 256, 2, 256>
        <<<32, 256, 0, stream>>>(bufA, bufB, w_d[4], bufC,
                                 st(9), g_c[4], b_c[4], iN4, st(10));
    pool2_kernel<256, 256><<<N5 * 64 / 256, 256, 0, stream>>>(
        bufC, pool[4], st(10), g_d[4], b_d[4], iN4, bufA, N5);

    // ---- conv6 256->512 (round-5: NCOT=8, ks=27)
    convd_kernel<256, 512, 64, 8, 4, 64, 256, 2, 1, false, false>
        <<<864, 256, 0, stream>>>(bufA, nbr[5], w_c[5], bufB, nullptr);
    reducek_kernel<512, 27><<<128, 256, 0, stream>>>(
        (const float4*)bufB, (float4*)bufB, N5 * 128, st(11));

    // ---- segment pooling (applies conv6 BN) -> z in bufC
    segpool2_kernel<<<8, 512, 0, stream>>>(bufB, st(11), g_c[5], b_c[5], iN5, bufC);

    // ---- f1
    zero_kernel<<<16, 256, 0, stream>>>(bufB, 4096);
    fc_kernel<1024, 512, 4, false><<<dim3(8, 4), 256, 0, stream>>>(
        bufC, w_f1, nullptr, nullptr, nullptr, 0.f, bufB);
    stats4_kernel<<<4, 256, 0, stream>>>((const float4*)bufB, 1024, 512, 128, st(12));

    // ---- f2
    zero_kernel<<<8, 256, 0, stream>>>(bufB + 4096, 2048);
    fc_kernel<512, 256, 4, true><<<dim3(4, 4), 256, 0, stream>>>(
        bufB, w_f2, st(12), g_f1, b_f1, i8, bufB + 4096);
    stats4_kernel<<<2, 256, 0, stream>>>(
        (const float4*)(bufB + 4096), 512, 256, 64, st(13));

    // ---- f3
    f3n_kernel<<<1, 256, 0, stream>>>(bufB + 4096, w_f3, bias_f3,
                                      st(13), g_f2, b_f2, i8, out);
}

// Round 9
// 1063.393 us; speedup vs baseline: 1.4058x; 1.1028x over previous
//
#include <hip/hip_runtime.h>
#include <math.h>

#define BN_EPS 1e-5f

// ---------------------------------------------------------------------------
// Round 9: round-8 base with conv2 reverted to round-5 non-PREF RT=2 config
// (PREF register double-buffer only fits CIN=16 -> conv1 only).
// ---------------------------------------------------------------------------

__device__ __forceinline__ void fma4(float s, const float4& w, float4& a) {
    a.x = fmaf(s, w.x, a.x);
    a.y = fmaf(s, w.y, a.y);
    a.z = fmaf(s, w.z, a.z);
    a.w = fmaf(s, w.w, a.w);
}

__device__ __forceinline__ float nlr(float x, float sc, float sh) {
    float t = fmaf(x, sc, sh);
    return fmaxf(t, 0.01f * t);
}

__device__ __forceinline__ void bn_coef(const float* __restrict__ sums,
                                        const float* __restrict__ g,
                                        const float* __restrict__ b,
                                        int C, int c, float inv_n,
                                        float& sc, float& sh) {
    float mean = sums[c] * inv_n;
    float var = fmaxf(fmaf(-mean, mean, sums[C + c] * inv_n), 0.f);
    sc = g[c] * rsqrtf(var + BN_EPS);
    sh = fmaf(-mean, sc, b[c]);
}

__global__ void zero_kernel(float* __restrict__ p, int n) {
    int i = blockIdx.x * blockDim.x + threadIdx.x;
    if (i < n) p[i] = 0.f;
}

// mlp1 with fused per-channel stats (wave shuffle reduce -> LDS -> global)
__global__ __launch_bounds__(256) void mlp1s_kernel(
    const float* __restrict__ x, const float* __restrict__ w,
    float* __restrict__ out, int N, float* __restrict__ sums) {
    __shared__ float ls[32];
    int tid = threadIdx.x;
    if (tid < 32) ls[tid] = 0.f;
    __syncthreads();
    int n = blockIdx.x * blockDim.x + tid;
    float o[16];
    if (n < N) {
        float x0 = x[n * 3], x1 = x[n * 3 + 1], x2 = x[n * 3 + 2];
        #pragma unroll
        for (int c = 0; c < 16; c++)
            o[c] = fmaf(x0, w[c], fmaf(x1, w[16 + c], x2 * w[32 + c]));
        #pragma unroll
        for (int c4 = 0; c4 < 4; c4++)
            *reinterpret_cast<float4*>(out + n * 16 + c4 * 4) =
                make_float4(o[c4 * 4], o[c4 * 4 + 1], o[c4 * 4 + 2], o[c4 * 4 + 3]);
    } else {
        #pragma unroll
        for (int c = 0; c < 16; c++) o[c] = 0.f;
    }
    float q[16];
    #pragma unroll
    for (int c = 0; c < 16; c++) q[c] = o[c] * o[c];
    #pragma unroll
    for (int m = 1; m < 64; m <<= 1) {
        #pragma unroll
        for (int c = 0; c < 16; c++) {
            o[c] += __shfl_xor(o[c], m, 64);
            q[c] += __shfl_xor(q[c], m, 64);
        }
    }
    if ((tid & 63) == 0) {
        #pragma unroll
        for (int c = 0; c < 16; c++) {
            atomicAdd(&ls[c], o[c]);
            atomicAdd(&ls[16 + c], q[c]);
        }
    }
    __syncthreads();
    if (tid < 32) atomicAdd(&sums[tid], ls[tid]);
}

// in-place BN+lrelu on fp32 y0 (C=16); one float4 per thread
__global__ void norm0_kernel(float4* __restrict__ y, int total4,
                             const float* __restrict__ sums, const float* __restrict__ g,
                             const float* __restrict__ b, float inv_n) {
    __shared__ float lsc[16], lsh[16];
    int tid = threadIdx.x;
    if (tid < 16) {
        float sc, sh;
        bn_coef(sums, g, b, 16, tid, inv_n, sc, sh);
        lsc[tid] = sc;
        lsh[tid] = sh;
    }
    __syncthreads();
    int i = blockIdx.x * blockDim.x + tid;
    if (i >= total4) return;
    int cb = (i & 3) * 4;
    float4 v = y[i];
    v.x = nlr(v.x, lsc[cb + 0], lsh[cb + 0]);
    v.y = nlr(v.y, lsc[cb + 1], lsh[cb + 1]);
    v.z = nlr(v.z, lsc[cb + 2], lsh[cb + 2]);
    v.w = nlr(v.w, lsc[cb + 3], lsh[cb + 3]);
    y[i] = v;
}

// per-channel sum & sumsq, float4; requires blockDim % C4 == 0
__global__ void stats4_kernel(const float4* __restrict__ x, int total4, int C, int C4,
                              float* __restrict__ sums) {
    __shared__ float ls[1024];
    int tid = threadIdx.x;
    for (int j = tid; j < 2 * C; j += blockDim.x) ls[j] = 0.f;
    __syncthreads();
    int stride = gridDim.x * blockDim.x;
    int i = blockIdx.x * blockDim.x + tid;
    int c4 = i % C4;
    float4 s = make_float4(0.f, 0.f, 0.f, 0.f);
    float4 q = make_float4(0.f, 0.f, 0.f, 0.f);
    for (; i < total4; i += stride) {
        float4 v = x[i];
        s.x += v.x; s.y += v.y; s.z += v.z; s.w += v.w;
        q.x = fmaf(v.x, v.x, q.x); q.y = fmaf(v.y, v.y, q.y);
        q.z = fmaf(v.z, v.z, q.z); q.w = fmaf(v.w, v.w, q.w);
    }
    int cb = c4 * 4;
    atomicAdd(&ls[cb + 0], s.x); atomicAdd(&ls[cb + 1], s.y);
    atomicAdd(&ls[cb + 2], s.z); atomicAdd(&ls[cb + 3], s.w);
    atomicAdd(&ls[C + cb + 0], q.x); atomicAdd(&ls[C + cb + 1], q.y);
    atomicAdd(&ls[C + cb + 2], q.z); atomicAdd(&ls[C + cb + 3], q.w);
    __syncthreads();
    for (int j = tid; j < 2 * C; j += blockDim.x) atomicAdd(&sums[j], ls[j]);
}

// reduce KS k-split partial slices + fused stats; out aliases slice 0
template <int C, int KS>
__global__ void reducek_kernel(const float4* __restrict__ in, float4* __restrict__ out,
                               int total4, float* __restrict__ sums) {
    __shared__ float ls[1024];
    constexpr int C4 = C / 4;
    int tid = threadIdx.x;
    for (int j = tid; j < 2 * C; j += blockDim.x) ls[j] = 0.f;
    __syncthreads();
    int stride = gridDim.x * blockDim.x;
    int i = blockIdx.x * blockDim.x + tid;
    int c4 = i % C4;
    float4 s = make_float4(0.f, 0.f, 0.f, 0.f);
    float4 q = make_float4(0.f, 0.f, 0.f, 0.f);
    for (; i < total4; i += stride) {
        float4 v = make_float4(0.f, 0.f, 0.f, 0.f);
        #pragma unroll
        for (int p = 0; p < KS; p++) {
            float4 t = in[(size_t)p * total4 + i];
            v.x += t.x; v.y += t.y; v.z += t.z; v.w += t.w;
        }
        out[i] = v;
        s.x += v.x; s.y += v.y; s.z += v.z; s.w += v.w;
        q.x = fmaf(v.x, v.x, q.x); q.y = fmaf(v.y, v.y, q.y);
        q.z = fmaf(v.z, v.z, q.z); q.w = fmaf(v.w, v.w, q.w);
    }
    int cb = c4 * 4;
    atomicAdd(&ls[cb + 0], s.x); atomicAdd(&ls[cb + 1], s.y);
    atomicAdd(&ls[cb + 2], s.z); atomicAdd(&ls[cb + 3], s.w);
    atomicAdd(&ls[C + cb + 0], q.x); atomicAdd(&ls[C + cb + 1], q.y);
    atomicAdd(&ls[C + cb + 2], q.z); atomicAdd(&ls[C + cb + 3], q.w);
    __syncthreads();
    for (int j = tid; j < 2 * C; j += blockDim.x) atomicAdd(&sums[j], ls[j]);
}

// ---------------------------------------------------------------------------
// Direct sparse conv, fp32 normalized input.  grid = NCOT*MT*KS.
// PREF (conv1 only, C4N==4): named double-buffered y lookahead, RT=1.
// ---------------------------------------------------------------------------
template <int CIN, int COUT, int CO_TILE, int NCOT, int MT, int TM, int NTHR,
          int NQ, int KT, bool STATS, bool PREF>
__global__ __launch_bounds__(NTHR) void convd_kernel(
    const float* __restrict__ y, const int* __restrict__ nbr,
    const float* __restrict__ w, float* __restrict__ out,
    float* __restrict__ s_out) {
    constexpr int CQT = CO_TILE / (4 * NQ);
    constexpr int MGRP = NTHR / CQT;
    constexpr int RT = TM / MGRP;
    constexpr int C4N = CIN / 4;
    static_assert(MGRP * RT == TM, "tile mismatch");
    static_assert(MGRP * CQT == NTHR, "thread mismatch");

    __shared__ float sred[STATS ? 2 * CO_TILE : 1];

    const int tid = threadIdx.x;
    const int bid = blockIdx.x;
    const int cot = bid % NCOT;
    const int rest = bid / NCOT;
    const int mt = rest % MT;
    const int ks = rest / MT;
    const int m0 = mt * TM;
    const int cobase = cot * CO_TILE;
    const int k0 = ks * KT;
    const int cq = tid % CQT;
    const int mg = tid / CQT;

    int mrow[RT];
    #pragma unroll
    for (int r = 0; r < RT; r++) mrow[r] = m0 + mg + r * MGRP;

    float4 acc[RT][NQ];
    #pragma unroll
    for (int r = 0; r < RT; r++)
        #pragma unroll
        for (int q = 0; q < NQ; q++) acc[r][q] = make_float4(0.f, 0.f, 0.f, 0.f);

    auto ldidx = [&](int k, int (&rr)[RT]) {
        #pragma unroll
        for (int r = 0; r < RT; r++) rr[r] = nbr[(size_t)mrow[r] * 27 + k];
    };

    if constexpr (PREF) {
        auto ldy = [&](const int (&rr)[RT], float4 (&yv)[RT][C4N]) {
            #pragma unroll
            for (int r = 0; r < RT; r++)
                #pragma unroll
                for (int c4 = 0; c4 < C4N; c4++)
                    yv[r][c4] = *reinterpret_cast<const float4*>(
                        y + (size_t)rr[r] * CIN + c4 * 4);
        };
        auto fmak = [&](int k, const float4 (&yv)[RT][C4N]) {
            const float* wk = w + (size_t)k * CIN * COUT + cobase + cq * (4 * NQ);
            #pragma unroll
            for (int c4 = 0; c4 < C4N; c4++) {
                #pragma unroll
                for (int jj = 0; jj < 4; jj++) {
                    #pragma unroll
                    for (int q = 0; q < NQ; q++) {
                        float4 wv = *reinterpret_cast<const float4*>(
                            wk + (size_t)(c4 * 4 + jj) * COUT + q * 4);
                        #pragma unroll
                        for (int r = 0; r < RT; r++) {
                            float e = jj == 0 ? yv[r][c4].x : jj == 1 ? yv[r][c4].y
                                     : jj == 2 ? yv[r][c4].z : yv[r][c4].w;
                            fma4(e, wv, acc[r][q]);
                        }
                    }
                }
            }
        };
        int ra[RT], rb[RT];
        float4 ya[RT][C4N], yb[RT][C4N];
        ldidx(k0, ra);
        ldy(ra, ya);
        int kk = 0;
        for (; kk + 2 <= KT; kk += 2) {
            ldidx(k0 + kk + 1, rb);
            ldy(rb, yb);
            fmak(k0 + kk, ya);
            if (kk + 2 < KT) {
                ldidx(k0 + kk + 2, ra);
                ldy(ra, ya);
            }
            fmak(k0 + kk + 1, yb);
        }
        if (KT & 1) fmak(k0 + KT - 1, ya);
    } else {
        int rows[RT];
        ldidx(k0, rows);
        for (int kk = k0; kk < k0 + KT; kk++) {
            int rnext[RT];
            if (kk + 1 < k0 + KT) ldidx(kk + 1, rnext);
            const float* wk = w + (size_t)kk * CIN * COUT + cobase + cq * (4 * NQ);
            #pragma unroll 4
            for (int c4 = 0; c4 < C4N; c4++) {
                float4 yv[RT];
                #pragma unroll
                for (int r = 0; r < RT; r++)
                    yv[r] = *reinterpret_cast<const float4*>(
                        y + (size_t)rows[r] * CIN + c4 * 4);
                #pragma unroll
                for (int jj = 0; jj < 4; jj++) {
                    #pragma unroll
                    for (int q = 0; q < NQ; q++) {
                        float4 wv = *reinterpret_cast<const float4*>(
                            wk + (size_t)(c4 * 4 + jj) * COUT + q * 4);
                        #pragma unroll
                        for (int r = 0; r < RT; r++) {
                            float e = jj == 0 ? yv[r].x : jj == 1 ? yv[r].y
                                     : jj == 2 ? yv[r].z : yv[r].w;
                            fma4(e, wv, acc[r][q]);
                        }
                    }
                }
            }
            #pragma unroll
            for (int r = 0; r < RT; r++) rows[r] = rnext[r];
        }
    }

    float* outp = out + (size_t)ks * MT * TM * COUT;
    #pragma unroll
    for (int r = 0; r < RT; r++)
        #pragma unroll
        for (int q = 0; q < NQ; q++)
            *reinterpret_cast<float4*>(
                outp + (size_t)mrow[r] * COUT + cobase + cq * (4 * NQ) + q * 4) =
                acc[r][q];

    if constexpr (STATS) {
        for (int j = tid; j < 2 * CO_TILE; j += NTHR) sred[j] = 0.f;
        __syncthreads();
        #pragma unroll
        for (int q = 0; q < NQ; q++) {
            float4 s = make_float4(0.f, 0.f, 0.f, 0.f);
            float4 qq = make_float4(0.f, 0.f, 0.f, 0.f);
            #pragma unroll
            for (int r = 0; r < RT; r++) {
                float4 v = acc[r][q];
                s.x += v.x; s.y += v.y; s.z += v.z; s.w += v.w;
                qq.x = fmaf(v.x, v.x, qq.x); qq.y = fmaf(v.y, v.y, qq.y);
                qq.z = fmaf(v.z, v.z, qq.z); qq.w = fmaf(v.w, v.w, qq.w);
            }
            int cb = cq * (4 * NQ) + q * 4;
            atomicAdd(&sred[cb + 0], s.x); atomicAdd(&sred[cb + 1], s.y);
            atomicAdd(&sred[cb + 2], s.z); atomicAdd(&sred[cb + 3], s.w);
            atomicAdd(&sred[CO_TILE + cb + 0], qq.x);
            atomicAdd(&sred[CO_TILE + cb + 1], qq.y);
            atomicAdd(&sred[CO_TILE + cb + 2], qq.z);
            atomicAdd(&sred[CO_TILE + cb + 3], qq.w);
        }
        __syncthreads();
        for (int j = tid; j < CO_TILE; j += NTHR) {
            atomicAdd(&s_out[cobase + j], sred[j]);
            atomicAdd(&s_out[COUT + cobase + j], sred[CO_TILE + j]);
        }
    }
}

// ---------------------------------------------------------------------------
// down (concat + 1x1): in1 = normalized y, in2 = raw conv out (inline norm).
// Fused output stats.
// ---------------------------------------------------------------------------
template <int C1, int C2, int COUT, int NQ, int NTHR>
__global__ __launch_bounds__(NTHR) void down3_kernel(
    const float* __restrict__ in1, const float* __restrict__ in2,
    const float* __restrict__ w, float* __restrict__ out,
    const float* __restrict__ s2, const float* __restrict__ g2,
    const float* __restrict__ b2, float inv2,
    float* __restrict__ s_out) {
    constexpr int CQT = COUT / (4 * NQ);
    constexpr int PAIRS = NTHR / CQT;
    __shared__ __align__(16) float n2c[C2], n2h[C2];
    __shared__ float sred[2 * COUT];

    const int tid = threadIdx.x;
    for (int c = tid; c < C2; c += NTHR) {
        float sc, sh;
        bn_coef(s2, g2, b2, C2, c, inv2, sc, sh);
        n2c[c] = sc; n2h[c] = sh;
    }
    for (int j = tid; j < 2 * COUT; j += NTHR) sred[j] = 0.f;
    __syncthreads();

    const int cq = tid % CQT;
    const int pr = tid / CQT;
    const int n0 = (blockIdx.x * PAIRS + pr) * 2;

    float4 acc[2][NQ];
    #pragma unroll
    for (int r = 0; r < 2; r++)
        #pragma unroll
        for (int q = 0; q < NQ; q++) acc[r][q] = make_float4(0.f, 0.f, 0.f, 0.f);

    const float* w1 = w + cq * (4 * NQ);
    #pragma unroll 8
    for (int ci4 = 0; ci4 < C1 / 4; ci4++) {
        float4 a0 = *reinterpret_cast<const float4*>(in1 + (size_t)n0 * C1 + ci4 * 4);
        float4 a1 = *reinterpret_cast<const float4*>(in1 + (size_t)(n0 + 1) * C1 + ci4 * 4);
        #pragma unroll
        for (int jj = 0; jj < 4; jj++) {
            const float* wp = w1 + (size_t)(ci4 * 4 + jj) * COUT;
            float e0 = jj == 0 ? a0.x : jj == 1 ? a0.y : jj == 2 ? a0.z : a0.w;
            float e1 = jj == 0 ? a1.x : jj == 1 ? a1.y : jj == 2 ? a1.z : a1.w;
            #pragma unroll
            for (int q = 0; q < NQ; q++) {
                float4 wv = *reinterpret_cast<const float4*>(wp + q * 4);
                fma4(e0, wv, acc[0][q]);
                fma4(e1, wv, acc[1][q]);
            }
        }
    }
    const float* w2 = w + (size_t)C1 * COUT + cq * (4 * NQ);
    #pragma unroll 8
    for (int ci4 = 0; ci4 < C2 / 4; ci4++) {
        float4 a0 = *reinterpret_cast<const float4*>(in2 + (size_t)n0 * C2 + ci4 * 4);
        float4 a1 = *reinterpret_cast<const float4*>(in2 + (size_t)(n0 + 1) * C2 + ci4 * 4);
        float4 sc = *reinterpret_cast<const float4*>(&n2c[ci4 * 4]);
        float4 sh = *reinterpret_cast<const float4*>(&n2h[ci4 * 4]);
        a0.x = nlr(a0.x, sc.x, sh.x); a0.y = nlr(a0.y, sc.y, sh.y);
        a0.z = nlr(a0.z, sc.z, sh.z); a0.w = nlr(a0.w, sc.w, sh.w);
        a1.x = nlr(a1.x, sc.x, sh.x); a1.y = nlr(a1.y, sc.y, sh.y);
        a1.z = nlr(a1.z, sc.z, sh.z); a1.w = nlr(a1.w, sc.w, sh.w);
        #pragma unroll
        for (int jj = 0; jj < 4; jj++) {
            const float* wp = w2 + (size_t)(ci4 * 4 + jj) * COUT;
            float e0 = jj == 0 ? a0.x : jj == 1 ? a0.y : jj == 2 ? a0.z : a0.w;
            float e1 = jj == 0 ? a1.x : jj == 1 ? a1.y : jj == 2 ? a1.z : a1.w;
            #pragma unroll
            for (int q = 0; q < NQ; q++) {
                float4 wv = *reinterpret_cast<const float4*>(wp + q * 4);
                fma4(e0, wv, acc[0][q]);
                fma4(e1, wv, acc[1][q]);
            }
        }
    }
    #pragma unroll
    for (int r = 0; r < 2; r++)
        #pragma unroll
        for (int q = 0; q < NQ; q++)
            *reinterpret_cast<float4*>(out + (size_t)(n0 + r) * COUT + cq * (4 * NQ) + q * 4) =
                acc[r][q];

    #pragma unroll
    for (int q = 0; q < NQ; q++) {
        float4 s = make_float4(0.f, 0.f, 0.f, 0.f);
        float4 qq = make_float4(0.f, 0.f, 0.f, 0.f);
        #pragma unroll
        for (int r = 0; r < 2; r++) {
            float4 v = acc[r][q];
            s.x += v.x; s.y += v.y; s.z += v.z; s.w += v.w;
            qq.x = fmaf(v.x, v.x, qq.x); qq.y = fmaf(v.y, v.y, qq.y);
            qq.z = fmaf(v.z, v.z, qq.z); qq.w = fmaf(v.w, v.w, qq.w);
        }
        int cb = cq * (4 * NQ) + q * 4;
        atomicAdd(&sred[cb + 0], s.x); atomicAdd(&sred[cb + 1], s.y);
        atomicAdd(&sred[cb + 2], s.z); atomicAdd(&sred[cb + 3], s.w);
        atomicAdd(&sred[COUT + cb + 0], qq.x);
        atomicAdd(&sred[COUT + cb + 1], qq.y);
        atomicAdd(&sred[COUT + cb + 2], qq.z);
        atomicAdd(&sred[COUT + cb + 3], qq.w);
    }
    __syncthreads();
    for (int j = tid; j < COUT; j += NTHR) {
        atomicAdd(&s_out[j], sred[j]);
        atomicAdd(&s_out[COUT + j], sred[COUT + j]);
    }
}

// ---------------------------------------------------------------------------
// pool: min/max over 27 raw rows, BN+lrelu by scale sign -> normalized y
// ---------------------------------------------------------------------------
template <int C, int NTHR>
__global__ __launch_bounds__(NTHR) void pool2_kernel(
    const float* __restrict__ draw, const int* __restrict__ pmap,
    const float* __restrict__ sums, const float* __restrict__ g,
    const float* __restrict__ b, float inv_n,
    float* __restrict__ yout, int Nout) {
    constexpr int C4 = C / 4;
    int i = blockIdx.x * NTHR + threadIdx.x;
    if (i >= Nout * C4) return;
    int n = i / C4, c4 = i % C4;
    float sc[4], sh[4];
    #pragma unroll
    for (int j = 0; j < 4; j++) bn_coef(sums, g, b, C, c4 * 4 + j, inv_n, sc[j], sh[j]);
    const int* pm = pmap + n * 27;
    float4 mn = make_float4(INFINITY, INFINITY, INFINITY, INFINITY);
    float4 mx = make_float4(-INFINITY, -INFINITY, -INFINITY, -INFINITY);
    #pragma unroll 9
    for (int k = 0; k < 27; k++) {
        int row = pm[k];
        float4 v = *reinterpret_cast<const float4*>(draw + (size_t)row * C + c4 * 4);
        mn.x = fminf(mn.x, v.x); mn.y = fminf(mn.y, v.y);
        mn.z = fminf(mn.z, v.z); mn.w = fminf(mn.w, v.w);
        mx.x = fmaxf(mx.x, v.x); mx.y = fmaxf(mx.y, v.y);
        mx.z = fmaxf(mx.z, v.z); mx.w = fmaxf(mx.w, v.w);
    }
    float4 o;
    o.x = nlr(sc[0] >= 0.f ? mx.x : mn.x, sc[0], sh[0]);
    o.y = nlr(sc[1] >= 0.f ? mx.y : mn.y, sc[1], sh[1]);
    o.z = nlr(sc[2] >= 0.f ? mx.z : mn.z, sc[2], sh[2]);
    o.w = nlr(sc[3] >= 0.f ? mx.w : mn.w, sc[3], sh[3]);
    *reinterpret_cast<float4*>(yout + (size_t)n * C + c4 * 4) = o;
}

__global__ void segpool2_kernel(const float* __restrict__ y,
                                const float* __restrict__ sums,
                                const float* __restrict__ g, const float* __restrict__ b,
                                float inv_n, float* __restrict__ z) {
    int bi = blockIdx.x;
    int c = threadIdx.x;  // 512
    float sc, sh;
    bn_coef(sums, g, b, 512, c, inv_n, sc, sh);
    float mn = INFINITY, mx = -INFINITY, sm = 0.f;
    for (int r = 0; r < 32; r++) {
        float v = y[(size_t)(bi * 32 + r) * 512 + c];
        mn = fminf(mn, v);
        mx = fmaxf(mx, v);
        sm += nlr(v, sc, sh);
    }
    z[bi * 1024 + c] = nlr(sc >= 0.f ? mx : mn, sc, sh);
    z[bi * 1024 + 512 + c] = sm * (1.f / 32.f);
}

// FC (M=8): grid (COUT/64, KSPLIT); optional input normalization at staging
template <int K, int COUT, int KSPLIT, bool NORM>
__global__ __launch_bounds__(256) void fc_kernel(
    const float* __restrict__ z, const float* __restrict__ w,
    const float* __restrict__ ns, const float* __restrict__ ng,
    const float* __restrict__ nb, float inv_n,
    float* __restrict__ out) {
    constexpr int KC = K / KSPLIT;
    constexpr int KG = KC / 16;
    __shared__ __align__(16) float zt[KC * 8];
    __shared__ float red[16 * 520];

    const int cobase = blockIdx.x * 64;
    const int kc0 = blockIdx.y * KC;
    const int tid = threadIdx.x;
    const int coq = tid & 15;
    const int kg = tid >> 4;

    for (int idx = tid; idx < 8 * (KC / 4); idx += 256) {
        int n = idx / (KC / 4);
        int kq = idx - n * (KC / 4);
        float4 v = *reinterpret_cast<const float4*>(z + (size_t)n * K + kc0 + kq * 4);
        if constexpr (NORM) {
            #pragma unroll
            for (int j = 0; j < 4; j++) {
                float sc, sh;
                bn_coef(ns, ng, nb, K, kc0 + kq * 4 + j, inv_n, sc, sh);
                float* pv = j == 0 ? &v.x : j == 1 ? &v.y : j == 2 ? &v.z : &v.w;
                *pv = nlr(*pv, sc, sh);
            }
        }
        zt[(kq * 4 + 0) * 8 + n] = v.x;
        zt[(kq * 4 + 1) * 8 + n] = v.y;
        zt[(kq * 4 + 2) * 8 + n] = v.z;
        zt[(kq * 4 + 3) * 8 + n] = v.w;
    }
    __syncthreads();

    float4 acc[8];
    #pragma unroll
    for (int n = 0; n < 8; n++) acc[n] = make_float4(0.f, 0.f, 0.f, 0.f);
    for (int ki = 0; ki < KG; ki++) {
        int k = kg * KG + ki;
        float4 wv = *reinterpret_cast<const float4*>(
            w + (size_t)(kc0 + k) * COUT + cobase + coq * 4);
        float4 za = *reinterpret_cast<const float4*>(&zt[k * 8]);
        float4 zb = *reinterpret_cast<const float4*>(&zt[k * 8 + 4]);
        fma4(za.x, wv, acc[0]); fma4(za.y, wv, acc[1]);
        fma4(za.z, wv, acc[2]); fma4(za.w, wv, acc[3]);
        fma4(zb.x, wv, acc[4]); fma4(zb.y, wv, acc[5]);
        fma4(zb.z, wv, acc[6]); fma4(zb.w, wv, acc[7]);
    }
    #pragma unroll
    for (int n = 0; n < 8; n++) {
        red[kg * 520 + (coq * 4 + 0) * 8 + n] = acc[n].x;
        red[kg * 520 + (coq * 4 + 1) * 8 + n] = acc[n].y;
        red[kg * 520 + (coq * 4 + 2) * 8 + n] = acc[n].z;
        red[kg * 520 + (coq * 4 + 3) * 8 + n] = acc[n].w;
    }
    __syncthreads();
    for (int oi = tid; oi < 512; oi += 256) {
        int c = oi >> 3;
        int n = oi & 7;
        float s = 0.f;
        #pragma unroll
        for (int gg = 0; gg < 16; gg++) s += red[gg * 520 + c * 8 + n];
        float* op = out + (size_t)n * COUT + cobase + c;
        if (KSPLIT > 1) atomicAdd(op, s);
        else *op = s;
    }
}

__global__ void f3n_kernel(const float* __restrict__ in, const float* __restrict__ w,
                           const float* __restrict__ bias,
                           const float* __restrict__ sums, const float* __restrict__ g,
                           const float* __restrict__ b, float inv_n,
                           float* __restrict__ out) {
    __shared__ float zin[8 * 256];
    int tid = threadIdx.x;  // 256
    for (int idx = tid; idx < 2048; idx += 256) {
        int c = idx & 255;
        float sc, sh;
        bn_coef(sums, g, b, 256, c, inv_n, sc, sh);
        zin[idx] = nlr(in[idx], sc, sh);
    }
    __syncthreads();
    if (tid >= 160) return;
    int n = tid / 20, co = tid % 20;
    float acc = bias[co];
    for (int ci = 0; ci < 256; ci++)
        acc = fmaf(zin[n * 256 + ci], w[ci * 20 + co], acc);
    out[tid] = acc;
}

// ---------------------------------------------------------------------------

extern "C" void kernel_launch(void* const* d_in, const int* in_sizes, int n_in,
                              void* d_out, int out_size, void* d_ws, size_t ws_size,
                              hipStream_t stream) {
    (void)in_sizes; (void)n_in; (void)out_size; (void)ws_size;

    const int N0 = 131072, N1 = 32768, N2 = 8192, N3 = 2048, N4 = 512, N5 = 256;

    const float* x      = (const float*)d_in[0];
    const float* w_mlp1 = (const float*)d_in[1];
    const float* g_mlp1 = (const float*)d_in[2];
    const float* b_mlp1 = (const float*)d_in[3];
    const float* w_c[6]; const float* g_c[6]; const float* b_c[6];
    for (int i = 0; i < 6; i++) {
        w_c[i] = (const float*)d_in[4 + 3 * i];
        g_c[i] = (const float*)d_in[5 + 3 * i];
        b_c[i] = (const float*)d_in[6 + 3 * i];
    }
    const float* w_d[5]; const float* g_d[5]; const float* b_d[5];
    for (int i = 0; i < 5; i++) {
        w_d[i] = (const float*)d_in[22 + 3 * i];
        g_d[i] = (const float*)d_in[23 + 3 * i];
        b_d[i] = (const float*)d_in[24 + 3 * i];
    }
    const float* w_f1 = (const float*)d_in[37];
    const float* g_f1 = (const float*)d_in[38];
    const float* b_f1 = (const float*)d_in[39];
    const float* w_f2 = (const float*)d_in[40];
    const float* g_f2 = (const float*)d_in[41];
    const float* b_f2 = (const float*)d_in[42];
    const float* w_f3 = (const float*)d_in[43];
    const float* bias_f3 = (const float*)d_in[44];
    const int* nbr[6];
    for (int i = 0; i < 6; i++) nbr[i] = (const int*)d_in[45 + i];
    const int* pool[5];
    for (int i = 0; i < 5; i++) pool[i] = (const int*)d_in[51 + i];

    float* ws    = (float*)d_ws;
    float* bufA  = ws;                    // normalized y levels
    float* bufB  = bufA + 2097152;        // conv finals + partial arena
    float* bufC  = bufB + 4194304;        // down raw / z / partial spill
    float* stats = bufC + 4194304;
    float* out = (float*)d_out;

    auto st = [&](int slot) { return stats + slot * 1024; };

    const float iN0 = 1.f / N0, iN1 = 1.f / N1, iN2 = 1.f / N2, iN3 = 1.f / N3,
                iN4 = 1.f / N4, iN5 = 1.f / N5, i8 = 1.f / 8.f;

    zero_kernel<<<56, 256, 0, stream>>>(stats, 14 * 1024);

    // ---- mlp1 raw -> bufA with fused stats; in-place normalize
    mlp1s_kernel<<<N0 / 256, 256, 0, stream>>>(x, w_mlp1, bufA, N0, st(0));
    norm0_kernel<<<N0 * 4 / 256, 256, 0, stream>>>(
        (float4*)bufA, N0 * 4, st(0), g_mlp1, b_mlp1, iN0);

    // ---- level 0: conv1 16->32 (PREF RT=1, 2048 blocks, fused stats)
    convd_kernel<16, 32, 32, 1, 2048, 64, 256, 2, 27, true, true>
        <<<2048, 256, 0, stream>>>(bufA, nbr[0], w_c[0], bufB, st(1));
    down3_kernel<16, 32, 32, 2, 256>
        <<<1024, 256, 0, stream>>>(bufA, bufB, w_d[0], bufC,
                                   st(1), g_c[0], b_c[0], iN0, st(2));
    pool2_kernel<32, 256><<<N1 * 8 / 256, 256, 0, stream>>>(
        bufC, pool[0], st(2), g_d[0], b_d[0], iN0, bufA, N1);

    // ---- level 1: conv2 32->48 (round-5 proven: non-PREF RT=2, ks=3 KT=9)
    convd_kernel<32, 48, 48, 1, 512, 64, 192, 2, 9, false, false>
        <<<1536, 192, 0, stream>>>(bufA, nbr[1], w_c[1], bufB, nullptr);
    reducek_kernel<48, 3><<<1024, 192, 0, stream>>>(
        (const float4*)bufB, (float4*)bufB, N1 * 12, st(3));
    down3_kernel<32, 48, 48, 2, 192>
        <<<512, 192, 0, stream>>>(bufA, bufB, w_d[1], bufC,
                                  st(3), g_c[1], b_c[1], iN1, st(4));
    pool2_kernel<48, 192><<<N2 * 12 / 192, 192, 0, stream>>>(
        bufC, pool[1], st(4), g_d[1], b_d[1], iN1, bufA, N2);

    // ---- level 2: conv3 48->96 (round-5: NCOT=2, ks=9, KT=3)
    convd_kernel<48, 96, 48, 2, 128, 64, 192, 2, 3, false, false>
        <<<2304, 192, 0, stream>>>(bufA, nbr[2], w_c[2], bufB, nullptr);
    reducek_kernel<96, 9><<<1024, 192, 0, stream>>>(
        (const float4*)bufB, (float4*)bufB, N2 * 24, st(5));
    down3_kernel<48, 96, 96, 2, 192>
        <<<256, 192, 0, stream>>>(bufA, bufB, w_d[2], bufC,
                                  st(5), g_c[2], b_c[2], iN2, st(6));
    pool2_kernel<96, 192><<<N3 * 24 / 192, 192, 0, stream>>>(
        bufC, pool[2], st(6), g_d[2], b_d[2], iN2, bufA, N3);

    // ---- level 3: conv4 96->128 (round-5: NCOT=2, ks=27, KT=1)
    convd_kernel<96, 128, 64, 2, 32, 64, 256, 2, 1, false, false>
        <<<1728, 256, 0, stream>>>(bufA, nbr[3], w_c[3], bufB, nullptr);
    reducek_kernel<128, 27><<<256, 256, 0, stream>>>(
        (const float4*)bufB, (float4*)bufB, N3 * 32, st(7));
    down3_kernel<96, 128, 128, 2, 256>
        <<<64, 256, 0, stream>>>(bufA, bufB, w_d[3], bufC,
                                 st(7), g_c[3], b_c[3], iN3, st(8));
    pool2_kernel<128, 256><<<N4 * 32 / 256, 256, 0, stream>>>(
        bufC, pool[3], st(8), g_d[3], b_d[3], iN3, bufA, N4);

    // ---- level 4: conv5 128->256 (round-5: NCOT=4, ks=27)
    convd_kernel<128, 256, 64, 4, 8, 64, 256, 2, 1, false, false>
        <<<864, 256, 0, stream>>>(bufA, nbr[4], w_c[4], bufB, nullptr);
    reducek_kernel<256, 27><<<128, 256, 0, stream>>>(
        (const float4*)bufB, (float4*)bufB, N4 * 64, st(9));
    down3_kernel<128, 256, 256, 2, 256>
        <<<32, 256, 0, stream>>>(bufA, bufB, w_d[4], bufC,
                                 st(9), g_c[4], b_c[4], iN4, st(10));
    pool2_kernel<256, 256><<<N5 * 64 / 256, 256, 0, stream>>>(
        bufC, pool[4], st(10), g_d[4], b_d[4], iN4, bufA, N5);

    // ---- conv6 256->512 (round-5: NCOT=8, ks=27)
    convd_kernel<256, 512, 64, 8, 4, 64, 256, 2, 1, false, false>
        <<<864, 256, 0, stream>>>(bufA, nbr[5], w_c[5], bufB, nullptr);
    reducek_kernel<512, 27><<<128, 256, 0, stream>>>(
        (const float4*)bufB, (float4*)bufB, N5 * 128, st(11));

    // ---- segment pooling (applies conv6 BN) -> z in bufC
    segpool2_kernel<<<8, 512, 0, stream>>>(bufB, st(11), g_c[5], b_c[5], iN5, bufC);

    // ---- f1
    zero_kernel<<<16, 256, 0, stream>>>(bufB, 4096);
    fc_kernel<1024, 512, 4, false><<<dim3(8, 4), 256, 0, stream>>>(
        bufC, w_f1, nullptr, nullptr, nullptr, 0.f, bufB);
    stats4_kernel<<<4, 256, 0, stream>>>((const float4*)bufB, 1024, 512, 128, st(12));

    // ---- f2
    zero_kernel<<<8, 256, 0, stream>>>(bufB + 4096, 2048);
    fc_kernel<512, 256, 4, true><<<dim3(4, 4), 256, 0, stream>>>(
        bufB, w_f2, st(12), g_f1, b_f1, i8, bufB + 4096);
    stats4_kernel<<<2, 256, 0, stream>>>(
        (const float4*)(bufB + 4096), 512, 256, 64, st(13));

    // ---- f3
    f3n_kernel<<<1, 256, 0, stream>>>(bufB + 4096, w_f3, bias_f3,
                                      st(13), g_f2, b_f2, i8, out);
}